// Round 1
// baseline (1498.417 us; speedup 1.0000x reference)
//
#include <hip/hip_runtime.h>
#include <math.h>

// Problem constants
#define B_   4
#define CIN  256
#define COUT 256
#define Hh   64
#define Ww   64
#define HW   4096   // 64*64

// Workspace layout (floats):
//   om   : B*27*HW       = 442368
//   xt   : B*HW*CIN      = 4194304   (x transposed to [b][hw][c])
//   wT   : 2304*COUT     = 589824    (w_dcn transposed to [ck][o], ck=c*9+k)
//   WT2  : 4*1024*COUT   = 1048576   (conv-transpose weights per parity, [pp][c*4+ab][o])
//   out1 : B*COUT*HW     = 4194304   (DCN output)
//   y1t  : B*HW*COUT     = 4194304   (BN1+relu output, transposed [b][hw][o])
//   st1  : 512  (mean,rstd per channel)
//   st2  : 512
// total ~58.7 MB

__device__ __forceinline__ float sigmoidf_(float v){ return 1.0f/(1.0f+expf(-v)); }

// ---------- transpose x [B][C][HW] -> xt [B][HW][C] ----------
__global__ void k_transpose_x(const float* __restrict__ x, float* __restrict__ xt){
  __shared__ float ts[32][33];
  int tx = threadIdx.x & 31, ty = threadIdx.x >> 5;
  int p0 = blockIdx.x * 32, c0 = blockIdx.y * 32, b = blockIdx.z;
  const float* xb = x + (size_t)b*CIN*HW;
  float* xo = xt + (size_t)b*HW*CIN;
#pragma unroll
  for(int q=0;q<4;q++){
    int c = ty + q*8;
    ts[c][tx] = xb[(size_t)(c0+c)*HW + p0+tx];
  }
  __syncthreads();
#pragma unroll
  for(int q=0;q<4;q++){
    int pr = ty + q*8;
    xo[(size_t)(p0+pr)*CIN + c0+tx] = ts[tx][pr];
  }
}

// ---------- offset conv: om[b][27][h][w] = conv3x3(x, w_off), channel-split + atomics ----------
// grid (16 tiles, 4 cgroups, B), block 256 = 16x16 pixels
__global__ void k_offset_conv(const float* __restrict__ x, const float* __restrict__ w_off,
                              float* __restrict__ om){
  __shared__ float xs[18*18];
  int tid = threadIdx.x;
  int tile = blockIdx.x, cg = blockIdx.y, b = blockIdx.z;
  int ty0 = (tile>>2)*16, tx0 = (tile&3)*16;
  int ty = tid>>4, tx = tid&15;
  float acc[27];
#pragma unroll
  for(int i=0;i<27;i++) acc[i]=0.f;
  for(int c = cg*64; c < cg*64+64; ++c){
    const float* xp = x + (size_t)(b*CIN + c)*HW;
    for(int i=tid;i<324;i+=256){
      int yy = ty0 - 1 + i/18, xx = tx0 - 1 + i%18;
      float v = 0.f;
      if(yy>=0 && yy<Hh && xx>=0 && xx<Ww) v = xp[yy*Ww+xx];
      xs[i] = v;
    }
    __syncthreads();
    float nb[9];
#pragma unroll
    for(int kh=0;kh<3;kh++)
#pragma unroll
      for(int kw=0;kw<3;kw++) nb[kh*3+kw] = xs[(ty+kh)*18 + tx+kw];
    const float* wp = w_off + (size_t)c*9;   // + oc*2304 below
#pragma unroll
    for(int oc=0;oc<27;oc++){
      const float* wq = wp + (size_t)oc*CIN*9;
      float s = acc[oc];
#pragma unroll
      for(int k=0;k<9;k++) s = fmaf(nb[k], wq[k], s);
      acc[oc] = s;
    }
    __syncthreads();
  }
  int h = ty0+ty, w = tx0+tx;
#pragma unroll
  for(int oc=0;oc<27;oc++)
    atomicAdd(&om[(size_t)(b*27+oc)*HW + h*Ww + w], acc[oc]);
}

// ---------- weight re-layouts ----------
__global__ void k_build_wT(const float* __restrict__ w_dcn, float* __restrict__ wT){
  int o = threadIdx.x; int ck = blockIdx.x;            // grid 2304, block 256
  wT[(size_t)ck*COUT + o] = w_dcn[(size_t)o*2304 + ck];
}
// WT2[pp][k=c*4 + a*2+b][o] = w_up[c][o][3-ph-2a][3-pw-2b]
__global__ void k_build_WT2(const float* __restrict__ w_up, float* __restrict__ WT2){
  int o = threadIdx.x;                                  // grid 4096, block 256
  int kk = blockIdx.x & 1023, pp = blockIdx.x >> 10;
  int c = kk>>2, ab = kk&3, a = ab>>1, bb = ab&1;
  int ph = pp>>1, pw = pp&1;
  WT2[(size_t)blockIdx.x*COUT + o] =
      w_up[(size_t)(c*COUT+o)*16 + (3-ph-2*a)*4 + (3-pw-2*bb)];
}

// ---------- DCN main GEMM: out1[b][o][p] = sum_ck val[ck][p] * wT[ck][o] + b_dcn ----------
// grid 256 (= 4 b * 64 px-tiles of 64), block 256; thread tile 8o x 8px; K=2304 in 16 chunks of 144
__global__ __launch_bounds__(256) void k_dcn(const float* __restrict__ xt, const float* __restrict__ om,
                      const float* __restrict__ b_off, const float* __restrict__ wT,
                      const float* __restrict__ b_dcn, float* __restrict__ out1){
  __shared__ int   sI[4][576];
  __shared__ float sC[4][576];
  __shared__ float val_s[144*68];
  int tid = threadIdx.x;
  int b = blockIdx.x >> 6;
  int px0 = (blockIdx.x & 63) * 64;

  // taps: t = k*64 + px  (9 taps x 64 pixels)
  for(int t=tid; t<576; t+=256){
    int k = t >> 6, px = t & 63;
    int p = px0 + px;
    int hh = p >> 6, ww = p & 63;
    const float* omp = om + (size_t)b*27*HW + p;
    float dy = omp[(size_t)k*HW]      + b_off[k];
    float dx = omp[(size_t)(9+k)*HW]  + b_off[9+k];
    float mo = sigmoidf_(omp[(size_t)(18+k)*HW] + b_off[18+k]);
    float py  = dy + (float)(hh + k/3 - 1);
    float pxf = dx + (float)(ww + k%3 - 1);
    float y0 = floorf(py), x0 = floorf(pxf);
    float wy = py - y0, wx = pxf - x0;
    float y1 = y0 + 1.0f, x1 = x0 + 1.0f;
    bool vy0 = (y0 >= 0.f) && (y0 <= 63.f);
    bool vy1 = (y1 >= 0.f) && (y1 <= 63.f);
    bool vx0 = (x0 >= 0.f) && (x0 <= 63.f);
    bool vx1 = (x1 >= 0.f) && (x1 <= 63.f);
    int iy0 = (int)fminf(fmaxf(y0,0.f),63.f);
    int iy1 = (int)fminf(fmaxf(y1,0.f),63.f);
    int ix0 = (int)fminf(fmaxf(x0,0.f),63.f);
    int ix1 = (int)fminf(fmaxf(x1,0.f),63.f);
    int base = b*HW;
    sI[0][t] = (base + iy0*64+ix0)*CIN; sC[0][t] = (vy0&&vx0)? (1.f-wy)*(1.f-wx)*mo : 0.f;
    sI[1][t] = (base + iy0*64+ix1)*CIN; sC[1][t] = (vy0&&vx1)? (1.f-wy)*wx*mo       : 0.f;
    sI[2][t] = (base + iy1*64+ix0)*CIN; sC[2][t] = (vy1&&vx0)? wy*(1.f-wx)*mo       : 0.f;
    sI[3][t] = (base + iy1*64+ix1)*CIN; sC[3][t] = (vy1&&vx1)? wy*wx*mo             : 0.f;
  }

  float acc[8][8];
#pragma unroll
  for(int i=0;i<8;i++)
#pragma unroll
    for(int j=0;j<8;j++) acc[i][j]=0.f;
  int o0 = (tid & 31) * 8;
  int q0 = (tid >> 5) * 8;

  for(int cc=0; cc<16; ++cc){
    __syncthreads();
    // stage 16 channels x 9 taps x 64 px
    for(int jj=0; jj<36; ++jj){
      int e = tid + jj*256;
      int ci = e & 15, t = e >> 4;
      int c = cc*16 + ci;
      float v = sC[0][t]*xt[sI[0][t]+c] + sC[1][t]*xt[sI[1][t]+c]
              + sC[2][t]*xt[sI[2][t]+c] + sC[3][t]*xt[sI[3][t]+c];
      int k = t >> 6, px = t & 63;
      val_s[(ci*9+k)*68 + px] = v;
    }
    __syncthreads();
    const float* wp = wT + (size_t)(cc*144)*COUT + o0;
#pragma unroll 2
    for(int ckl=0; ckl<144; ++ckl){
      float4 w0 = *(const float4*)(wp + (size_t)ckl*COUT);
      float4 w1 = *(const float4*)(wp + (size_t)ckl*COUT + 4);
      float4 v0 = *(const float4*)(&val_s[ckl*68 + q0]);
      float4 v1 = *(const float4*)(&val_s[ckl*68 + q0 + 4]);
      float wv[8] = {w0.x,w0.y,w0.z,w0.w,w1.x,w1.y,w1.z,w1.w};
      float vv[8] = {v0.x,v0.y,v0.z,v0.w,v1.x,v1.y,v1.z,v1.w};
#pragma unroll
      for(int i=0;i<8;i++)
#pragma unroll
        for(int j=0;j<8;j++) acc[i][j] = fmaf(wv[i], vv[j], acc[i][j]);
    }
  }

#pragma unroll
  for(int i=0;i<8;i++){
    int o = o0 + i;
    float bias = b_dcn[o];
    float* op = out1 + (size_t)(b*COUT + o)*HW + px0 + q0;
    float4 r0 = make_float4(acc[i][0]+bias, acc[i][1]+bias, acc[i][2]+bias, acc[i][3]+bias);
    float4 r1 = make_float4(acc[i][4]+bias, acc[i][5]+bias, acc[i][6]+bias, acc[i][7]+bias);
    *(float4*)op = r0; *(float4*)(op+4) = r1;
  }
}

// ---------- batchnorm stats: per channel o over [B][per_b] ----------
__global__ void k_bn_stats(const float* __restrict__ xin, float* __restrict__ stats, int per_b){
  int o = blockIdx.x, tid = threadIdx.x;
  float s=0.f, ss=0.f;
  for(int b=0;b<B_;b++){
    const float* p = xin + (size_t)(b*COUT+o)*per_b;
    for(int i=tid;i<per_b;i+=256){ float v = p[i]; s+=v; ss+=v*v; }
  }
  __shared__ float rs[256], rss[256];
  rs[tid]=s; rss[tid]=ss; __syncthreads();
  for(int st=128; st>0; st>>=1){
    if(tid<st){ rs[tid]+=rs[tid+st]; rss[tid]+=rss[tid+st]; }
    __syncthreads();
  }
  if(tid==0){
    float n = (float)(B_*per_b);
    float mean = rs[0]/n;
    float var  = rss[0]/n - mean*mean;
    stats[o*2] = mean; stats[o*2+1] = rsqrtf(var + 1e-5f);
  }
}

// ---------- BN1 apply + relu + transpose out1[b][o][p] -> y1t[b][p][o] ----------
__global__ void k_bn1_apply_t(const float* __restrict__ out1, const float* __restrict__ stats,
                              const float* __restrict__ gamma, const float* __restrict__ beta,
                              float* __restrict__ y1t){
  __shared__ float ts[32][33];
  int tx = threadIdx.x & 31, ty = threadIdx.x >> 5;
  int p0 = blockIdx.x*32, o0 = blockIdx.y*32, b = blockIdx.z;
#pragma unroll
  for(int q=0;q<4;q++){
    int oo = ty + q*8; int o = o0 + oo;
    float m = stats[o*2], rstd = stats[o*2+1];
    float scale = rstd * gamma[o];
    float shift = beta[o] - m * scale;
    float v = out1[(size_t)(b*COUT+o)*HW + p0+tx];
    ts[oo][tx] = fmaxf(v*scale + shift, 0.f);
  }
  __syncthreads();
#pragma unroll
  for(int q=0;q<4;q++){
    int pr = ty + q*8;
    y1t[(size_t)(b*HW + p0+pr)*COUT + o0+tx] = ts[tx][pr];
  }
}

// ---------- conv-transpose GEMM per parity: K = 256c*4taps = 1024 ----------
// grid 1024 (= 64 px-tiles * 4 b * 4 parities), block 256; thread tile 8o x 8px
__global__ __launch_bounds__(256) void k_convt(const float* __restrict__ y1t, const float* __restrict__ WT2,
                        float* __restrict__ out){
  __shared__ int   sI[256];
  __shared__ float sC[256];
  __shared__ float val_s[64*68];
  int tid = threadIdx.x;
  int bidx = blockIdx.x;
  int pp = bidx & 3, b = (bidx>>2)&3, px0 = (bidx>>4)*64;
  int ph = pp>>1, pw = pp&1;

  { // taps: t = ab*64 + px
    int t = tid;
    int ab = t>>6, px = t&63;
    int a = ab>>1, bb = ab&1;
    int p = px0+px, r = p>>6, s = p&63;
    int ih = r + ph - 1 + a, iw = s + pw - 1 + bb;
    bool valid = (ih>=0 && ih<64 && iw>=0 && iw<64);
    sI[t] = valid ? (b*HW + ih*64+iw)*COUT : 0;
    sC[t] = valid ? 1.f : 0.f;
  }

  float acc[8][8];
#pragma unroll
  for(int i=0;i<8;i++)
#pragma unroll
    for(int j=0;j<8;j++) acc[i][j]=0.f;
  int o0 = (tid & 31) * 8;
  int q0 = (tid >> 5) * 8;
  const float* wbase = WT2 + (size_t)pp*1024*COUT;

  for(int cc=0; cc<16; ++cc){
    __syncthreads();
    for(int jj=0; jj<16; ++jj){
      int e = tid + jj*256;
      int ci = e & 15, t = e >> 4;
      int c = cc*16 + ci;
      float v = sC[t] * y1t[sI[t]+c];
      int ab = t>>6, px = t&63;
      val_s[(ci*4+ab)*68 + px] = v;
    }
    __syncthreads();
    const float* wp = wbase + (size_t)(cc*64)*COUT + o0;
#pragma unroll 2
    for(int ckl=0; ckl<64; ++ckl){
      float4 w0 = *(const float4*)(wp + (size_t)ckl*COUT);
      float4 w1 = *(const float4*)(wp + (size_t)ckl*COUT + 4);
      float4 v0 = *(const float4*)(&val_s[ckl*68 + q0]);
      float4 v1 = *(const float4*)(&val_s[ckl*68 + q0 + 4]);
      float wv[8] = {w0.x,w0.y,w0.z,w0.w,w1.x,w1.y,w1.z,w1.w};
      float vv[8] = {v0.x,v0.y,v0.z,v0.w,v1.x,v1.y,v1.z,v1.w};
#pragma unroll
      for(int i=0;i<8;i++)
#pragma unroll
        for(int j=0;j<8;j++) acc[i][j] = fmaf(wv[i], vv[j], acc[i][j]);
    }
  }

  // scatter epilogue: out[b][o][2r+ph][2s+pw]
#pragma unroll
  for(int i=0;i<8;i++){
    int o = o0 + i;
    float* op = out + (size_t)(b*COUT+o)*128*128;
#pragma unroll
    for(int j=0;j<8;j++){
      int p = px0 + q0 + j, r = p>>6, s = p&63;
      op[(2*r+ph)*128 + (2*s+pw)] = acc[i][j];
    }
  }
}

// ---------- BN2 apply + relu, in place on out [B][COUT][16384] ----------
__global__ void k_bn2_apply(float* __restrict__ out, const float* __restrict__ stats,
                            const float* __restrict__ gamma, const float* __restrict__ beta){
  size_t gid = (size_t)blockIdx.x*256 + threadIdx.x;
  size_t e = gid*4;
  int o = (int)((e >> 14) & 255);
  float m = stats[o*2], rstd = stats[o*2+1];
  float scale = rstd * gamma[o];
  float shift = beta[o] - m * scale;
  float4 v = *(float4*)(out+e);
  v.x = fmaxf(v.x*scale + shift, 0.f);
  v.y = fmaxf(v.y*scale + shift, 0.f);
  v.z = fmaxf(v.z*scale + shift, 0.f);
  v.w = fmaxf(v.w*scale + shift, 0.f);
  *(float4*)(out+e) = v;
}

extern "C" void kernel_launch(void* const* d_in, const int* in_sizes, int n_in,
                              void* d_out, int out_size, void* d_ws, size_t ws_size,
                              hipStream_t stream){
  (void)in_sizes; (void)n_in; (void)out_size; (void)ws_size;
  const float* x     = (const float*)d_in[0];
  const float* w_off = (const float*)d_in[1];
  const float* b_off = (const float*)d_in[2];
  const float* w_dcn = (const float*)d_in[3];
  const float* b_dcn = (const float*)d_in[4];
  const float* gamma1= (const float*)d_in[5];
  const float* beta1 = (const float*)d_in[6];
  const float* w_up  = (const float*)d_in[7];
  const float* gamma2= (const float*)d_in[8];
  const float* beta2 = (const float*)d_in[9];
  float* out = (float*)d_out;

  float* ws   = (float*)d_ws;
  float* om   = ws;                       // 442368
  float* xt   = om  + 442368;             // 4194304
  float* wT   = xt  + 4194304;            // 589824
  float* WT2  = wT  + 589824;             // 1048576
  float* out1 = WT2 + 1048576;            // 4194304
  float* y1t  = out1+ 4194304;            // 4194304
  float* st1  = y1t + 4194304;            // 512
  float* st2  = st1 + 512;                // 512

  hipMemsetAsync(om, 0, (size_t)442368*sizeof(float), stream);
  k_transpose_x <<<dim3(128,8,4), 256, 0, stream>>>(x, xt);
  k_offset_conv <<<dim3(16,4,4),  256, 0, stream>>>(x, w_off, om);
  k_build_wT    <<<2304, 256, 0, stream>>>(w_dcn, wT);
  k_build_WT2   <<<4096, 256, 0, stream>>>(w_up, WT2);
  k_dcn         <<<256,  256, 0, stream>>>(xt, om, b_off, wT, b_dcn, out1);
  k_bn_stats    <<<256,  256, 0, stream>>>(out1, st1, 4096);
  k_bn1_apply_t <<<dim3(128,8,4), 256, 0, stream>>>(out1, st1, gamma1, beta1, y1t);
  k_convt       <<<1024, 256, 0, stream>>>(y1t, WT2, out);
  k_bn_stats    <<<256,  256, 0, stream>>>(out, st2, 16384);
  k_bn2_apply   <<<16384,256, 0, stream>>>(out, st2, gamma2, beta2);
}

// Round 2
// 980.353 us; speedup vs baseline: 1.5284x; 1.5284x over previous
//
#include <hip/hip_runtime.h>
#include <hip/hip_bf16.h>
#include <math.h>

// Problem constants
#define B_   4
#define CIN  256
#define COUT 256
#define Hh   64
#define Ww   64
#define HW   4096   // 64*64

typedef __attribute__((ext_vector_type(8))) short short8;
typedef __attribute__((ext_vector_type(4))) float float4v;

// Workspace layout (floats):
//   om   : B*27*HW       = 442368
//   xt   : B*HW*CIN      = 4194304   (x transposed to [b][hw][c])
//   wT   : 2304*COUT     = 589824    (w_dcn transposed to [ck][o])
//   out1 : B*COUT*HW     = 4194304   (DCN output)
//   y1b  : B*HW*COUT bf16 = 2097152 floats (BN1+relu, transposed [b][p][c], bf16)
//   WT2c : 4*32*256*32 bf16 = 524288 floats (convT weights, [pp][kc][o][kk])
//   st1  : 512
//   st2  : 512
// total ~48.2 MB

__device__ __forceinline__ float sigmoidf_(float v){ return 1.0f/(1.0f+expf(-v)); }

// ---------- transpose x [B][C][HW] -> xt [B][HW][C] ----------
__global__ void k_transpose_x(const float* __restrict__ x, float* __restrict__ xt){
  __shared__ float ts[32][33];
  int tx = threadIdx.x & 31, ty = threadIdx.x >> 5;
  int p0 = blockIdx.x * 32, c0 = blockIdx.y * 32, b = blockIdx.z;
  const float* xb = x + (size_t)b*CIN*HW;
  float* xo = xt + (size_t)b*HW*CIN;
#pragma unroll
  for(int q=0;q<4;q++){
    int c = ty + q*8;
    ts[c][tx] = xb[(size_t)(c0+c)*HW + p0+tx];
  }
  __syncthreads();
#pragma unroll
  for(int q=0;q<4;q++){
    int pr = ty + q*8;
    xo[(size_t)(p0+pr)*CIN + c0+tx] = ts[tx][pr];
  }
}

// ---------- offset conv ----------
__global__ void k_offset_conv(const float* __restrict__ x, const float* __restrict__ w_off,
                              float* __restrict__ om){
  __shared__ float xs[18*18];
  int tid = threadIdx.x;
  int tile = blockIdx.x, cg = blockIdx.y, b = blockIdx.z;
  int ty0 = (tile>>2)*16, tx0 = (tile&3)*16;
  int ty = tid>>4, tx = tid&15;
  float acc[27];
#pragma unroll
  for(int i=0;i<27;i++) acc[i]=0.f;
  for(int c = cg*64; c < cg*64+64; ++c){
    const float* xp = x + (size_t)(b*CIN + c)*HW;
    for(int i=tid;i<324;i+=256){
      int yy = ty0 - 1 + i/18, xx = tx0 - 1 + i%18;
      float v = 0.f;
      if(yy>=0 && yy<Hh && xx>=0 && xx<Ww) v = xp[yy*Ww+xx];
      xs[i] = v;
    }
    __syncthreads();
    float nb[9];
#pragma unroll
    for(int kh=0;kh<3;kh++)
#pragma unroll
      for(int kw=0;kw<3;kw++) nb[kh*3+kw] = xs[(ty+kh)*18 + tx+kw];
    const float* wp = w_off + (size_t)c*9;
#pragma unroll
    for(int oc=0;oc<27;oc++){
      const float* wq = wp + (size_t)oc*CIN*9;
      float s = acc[oc];
#pragma unroll
      for(int k=0;k<9;k++) s = fmaf(nb[k], wq[k], s);
      acc[oc] = s;
    }
    __syncthreads();
  }
  int h = ty0+ty, w = tx0+tx;
#pragma unroll
  for(int oc=0;oc<27;oc++)
    atomicAdd(&om[(size_t)(b*27+oc)*HW + h*Ww + w], acc[oc]);
}

// ---------- weight re-layouts ----------
__global__ void k_build_wT(const float* __restrict__ w_dcn, float* __restrict__ wT){
  int o = threadIdx.x; int ck = blockIdx.x;            // grid 2304, block 256
  wT[(size_t)ck*COUT + o] = w_dcn[(size_t)o*2304 + ck];
}
// WT2c[pp][kc][o][kk] bf16, K order k = ab*256 + c (ab = a*2+b tap index)
// value = w_up[c][o][3-ph-2a][3-pw-2b]
__global__ void k_build_WT2c(const float* __restrict__ w_up, __hip_bfloat16* __restrict__ WT2c){
  int f = blockIdx.x*256 + threadIdx.x;    // grid 4096, block 256 -> 1,048,576
  int pp = f>>18;
  int kc = (f>>13)&31;
  int o  = (f>>5)&255;
  int kk = f&31;
  int k  = kc*32 + kk;
  int ab = k>>8, c = k&255;
  int a = ab>>1, bb = ab&1;
  int ph = pp>>1, pw = pp&1;
  float v = w_up[(size_t)(c*COUT+o)*16 + (3-ph-2*a)*4 + (3-pw-2*bb)];
  WT2c[f] = __float2bfloat16(v);
}

// ---------- DCN main GEMM (fp32, unchanged this round) ----------
__global__ __launch_bounds__(256) void k_dcn(const float* __restrict__ xt, const float* __restrict__ om,
                      const float* __restrict__ b_off, const float* __restrict__ wT,
                      const float* __restrict__ b_dcn, float* __restrict__ out1){
  __shared__ int   sI[4][576];
  __shared__ float sC[4][576];
  __shared__ float val_s[144*68];
  int tid = threadIdx.x;
  int b = blockIdx.x >> 6;
  int px0 = (blockIdx.x & 63) * 64;

  for(int t=tid; t<576; t+=256){
    int k = t >> 6, px = t & 63;
    int p = px0 + px;
    int hh = p >> 6, ww = p & 63;
    const float* omp = om + (size_t)b*27*HW + p;
    float dy = omp[(size_t)k*HW]      + b_off[k];
    float dx = omp[(size_t)(9+k)*HW]  + b_off[9+k];
    float mo = sigmoidf_(omp[(size_t)(18+k)*HW] + b_off[18+k]);
    float py  = dy + (float)(hh + k/3 - 1);
    float pxf = dx + (float)(ww + k%3 - 1);
    float y0 = floorf(py), x0 = floorf(pxf);
    float wy = py - y0, wx = pxf - x0;
    float y1 = y0 + 1.0f, x1 = x0 + 1.0f;
    bool vy0 = (y0 >= 0.f) && (y0 <= 63.f);
    bool vy1 = (y1 >= 0.f) && (y1 <= 63.f);
    bool vx0 = (x0 >= 0.f) && (x0 <= 63.f);
    bool vx1 = (x1 >= 0.f) && (x1 <= 63.f);
    int iy0 = (int)fminf(fmaxf(y0,0.f),63.f);
    int iy1 = (int)fminf(fmaxf(y1,0.f),63.f);
    int ix0 = (int)fminf(fmaxf(x0,0.f),63.f);
    int ix1 = (int)fminf(fmaxf(x1,0.f),63.f);
    int base = b*HW;
    sI[0][t] = (base + iy0*64+ix0)*CIN; sC[0][t] = (vy0&&vx0)? (1.f-wy)*(1.f-wx)*mo : 0.f;
    sI[1][t] = (base + iy0*64+ix1)*CIN; sC[1][t] = (vy0&&vx1)? (1.f-wy)*wx*mo       : 0.f;
    sI[2][t] = (base + iy1*64+ix0)*CIN; sC[2][t] = (vy1&&vx0)? wy*(1.f-wx)*mo       : 0.f;
    sI[3][t] = (base + iy1*64+ix1)*CIN; sC[3][t] = (vy1&&vx1)? wy*wx*mo             : 0.f;
  }

  float acc[8][8];
#pragma unroll
  for(int i=0;i<8;i++)
#pragma unroll
    for(int j=0;j<8;j++) acc[i][j]=0.f;
  int o0 = (tid & 31) * 8;
  int q0 = (tid >> 5) * 8;

  for(int cc=0; cc<16; ++cc){
    __syncthreads();
    for(int jj=0; jj<36; ++jj){
      int e = tid + jj*256;
      int ci = e & 15, t = e >> 4;
      int c = cc*16 + ci;
      float v = sC[0][t]*xt[sI[0][t]+c] + sC[1][t]*xt[sI[1][t]+c]
              + sC[2][t]*xt[sI[2][t]+c] + sC[3][t]*xt[sI[3][t]+c];
      int k = t >> 6, px = t & 63;
      val_s[(ci*9+k)*68 + px] = v;
    }
    __syncthreads();
    const float* wp = wT + (size_t)(cc*144)*COUT + o0;
#pragma unroll 2
    for(int ckl=0; ckl<144; ++ckl){
      float4 w0 = *(const float4*)(wp + (size_t)ckl*COUT);
      float4 w1 = *(const float4*)(wp + (size_t)ckl*COUT + 4);
      float4 v0 = *(const float4*)(&val_s[ckl*68 + q0]);
      float4 v1 = *(const float4*)(&val_s[ckl*68 + q0 + 4]);
      float wv[8] = {w0.x,w0.y,w0.z,w0.w,w1.x,w1.y,w1.z,w1.w};
      float vv[8] = {v0.x,v0.y,v0.z,v0.w,v1.x,v1.y,v1.z,v1.w};
#pragma unroll
      for(int i=0;i<8;i++)
#pragma unroll
        for(int j=0;j<8;j++) acc[i][j] = fmaf(wv[i], vv[j], acc[i][j]);
    }
  }

#pragma unroll
  for(int i=0;i<8;i++){
    int o = o0 + i;
    float bias = b_dcn[o];
    float* op = out1 + (size_t)(b*COUT + o)*HW + px0 + q0;
    float4 r0 = make_float4(acc[i][0]+bias, acc[i][1]+bias, acc[i][2]+bias, acc[i][3]+bias);
    float4 r1 = make_float4(acc[i][4]+bias, acc[i][5]+bias, acc[i][6]+bias, acc[i][7]+bias);
    *(float4*)op = r0; *(float4*)(op+4) = r1;
  }
}

// ---------- batchnorm stats ----------
__global__ void k_bn_stats(const float* __restrict__ xin, float* __restrict__ stats, int per_b){
  int o = blockIdx.x, tid = threadIdx.x;
  float s=0.f, ss=0.f;
  for(int b=0;b<B_;b++){
    const float* p = xin + (size_t)(b*COUT+o)*per_b;
    for(int i=tid;i<per_b;i+=256){ float v = p[i]; s+=v; ss+=v*v; }
  }
  __shared__ float rs[256], rss[256];
  rs[tid]=s; rss[tid]=ss; __syncthreads();
  for(int st=128; st>0; st>>=1){
    if(tid<st){ rs[tid]+=rs[tid+st]; rss[tid]+=rss[tid+st]; }
    __syncthreads();
  }
  if(tid==0){
    float n = (float)(B_*per_b);
    float mean = rs[0]/n;
    float var  = rss[0]/n - mean*mean;
    stats[o*2] = mean; stats[o*2+1] = rsqrtf(var + 1e-5f);
  }
}

// ---------- BN1 apply + relu + transpose -> y1b bf16 [b][p][c] ----------
__global__ void k_bn1_apply_t(const float* __restrict__ out1, const float* __restrict__ stats,
                              const float* __restrict__ gamma, const float* __restrict__ beta,
                              __hip_bfloat16* __restrict__ y1b){
  __shared__ float ts[32][33];
  int tx = threadIdx.x & 31, ty = threadIdx.x >> 5;
  int p0 = blockIdx.x*32, o0 = blockIdx.y*32, b = blockIdx.z;
#pragma unroll
  for(int q=0;q<4;q++){
    int oo = ty + q*8; int o = o0 + oo;
    float m = stats[o*2], rstd = stats[o*2+1];
    float scale = rstd * gamma[o];
    float shift = beta[o] - m * scale;
    float v = out1[(size_t)(b*COUT+o)*HW + p0+tx];
    ts[oo][tx] = fmaxf(v*scale + shift, 0.f);
  }
  __syncthreads();
#pragma unroll
  for(int q=0;q<4;q++){
    int pr = ty + q*8;
    y1b[((size_t)(b*HW + p0+pr)<<8) + o0+tx] = __float2bfloat16(ts[tx][pr]);
  }
}

// ---------- conv-transpose GEMM, MFMA bf16 ----------
// grid (64 px-tiles, 4 b, 4 pp), block 256 = 4 waves.
// Block tile: M=256 (all o), N=64 px, K=1024 (k = ab*256 + c), BK=32.
// Wave w computes o in [w*64, w*64+64) x all 64 px: 4x4 tiles of 16x16.
#define LSTR 48   // LDS row stride in bf16 (96 B: 16B-aligned, non-pow2 banks)
__global__ __launch_bounds__(256) void k_convt_mfma(const __hip_bfloat16* __restrict__ y1b,
                        const __hip_bfloat16* __restrict__ WT2c,
                        float* __restrict__ out){
  __shared__ ushort Ws[256*LSTR];   // [o][kk]
  __shared__ ushort Vs[64*LSTR];    // [px][kk]
  __shared__ int sIdx[256];         // [ab][px] -> bf16-elem offset into y1b, or -1
  int tid = threadIdx.x;
  int px0 = blockIdx.x * 64;
  int b   = blockIdx.y;
  int pp  = blockIdx.z;
  int ph = pp>>1, pw = pp&1;

  {
    int ab = tid>>6, px = tid&63;
    int a = ab>>1, bb = ab&1;
    int p = px0+px, r = p>>6, s = p&63;
    int ih = r + ph - 1 + a, iw = s + pw - 1 + bb;
    bool valid = (ih>=0 && ih<64 && iw>=0 && iw<64);
    sIdx[tid] = valid ? ((b*HW + ih*64+iw)<<8) : -1;
  }

  int lane = tid & 63, wv = tid >> 6;
  int lo = lane & 15, hi = lane >> 4;
  float4v acc[4][4];
#pragma unroll
  for(int i=0;i<4;i++)
#pragma unroll
    for(int j=0;j<4;j++) acc[i][j] = (float4v){0.f,0.f,0.f,0.f};

  int vpx = tid >> 2, vseg = tid & 3;
  const ushort* wbase = (const ushort*)WT2c + ((size_t)pp<<18);
  const ushort* ysrc  = (const ushort*)y1b;

  for(int kc=0; kc<32; ++kc){
    __syncthreads();
    // stage weights: contiguous 16 KB chunk [o][kk]
    {
      const ushort* wp = wbase + (kc<<13);
#pragma unroll
      for(int it=0; it<4; ++it){
        int g = tid + it*256;             // 8-bf16 group
        uint4 v = *(const uint4*)(wp + g*8);
        *(uint4*)(&Ws[(g>>2)*LSTR + (g&3)*8]) = v;
      }
    }
    // stage vals: gather 64 px x 32 c (tap ab = kc>>3, c0 = (kc&7)*32)
    {
      int ab = kc>>3, c0 = (kc&7)<<5;
      int idx = sIdx[(ab<<6) + vpx];
      uint4 v = make_uint4(0u,0u,0u,0u);
      if(idx >= 0) v = *(const uint4*)(ysrc + idx + c0 + vseg*8);
      *(uint4*)(&Vs[vpx*LSTR + vseg*8]) = v;
    }
    __syncthreads();

    const ushort* ap = &Ws[(wv*64 + lo)*LSTR + hi*8];
    const ushort* bp = &Vs[lo*LSTR + hi*8];
    short8 bfr[4];
#pragma unroll
    for(int j=0;j<4;j++) bfr[j] = *(const short8*)(bp + j*16*LSTR);
#pragma unroll
    for(int i=0;i<4;i++){
      short8 afr = *(const short8*)(ap + i*16*LSTR);
#pragma unroll
      for(int j=0;j<4;j++)
        acc[i][j] = __builtin_amdgcn_mfma_f32_16x16x32_bf16(afr, bfr[j], acc[i][j], 0,0,0);
    }
  }

  // epilogue: D row=(lane>>4)*4+reg -> o, col=lane&15 -> px
#pragma unroll
  for(int i=0;i<4;i++){
    int ob = wv*64 + i*16 + hi*4;
#pragma unroll
    for(int r=0;r<4;r++){
      float* op = out + (((size_t)(b*COUT + ob + r))<<14);
#pragma unroll
      for(int j=0;j<4;j++){
        int p = px0 + j*16 + lo;
        int rr = p>>6, ss = p&63;
        op[(2*rr+ph)*128 + (2*ss+pw)] = acc[i][j][r];
      }
    }
  }
}

// ---------- BN2 apply + relu ----------
__global__ void k_bn2_apply(float* __restrict__ out, const float* __restrict__ stats,
                            const float* __restrict__ gamma, const float* __restrict__ beta){
  size_t gid = (size_t)blockIdx.x*256 + threadIdx.x;
  size_t e = gid*4;
  int o = (int)((e >> 14) & 255);
  float m = stats[o*2], rstd = stats[o*2+1];
  float scale = rstd * gamma[o];
  float shift = beta[o] - m * scale;
  float4 v = *(float4*)(out+e);
  v.x = fmaxf(v.x*scale + shift, 0.f);
  v.y = fmaxf(v.y*scale + shift, 0.f);
  v.z = fmaxf(v.z*scale + shift, 0.f);
  v.w = fmaxf(v.w*scale + shift, 0.f);
  *(float4*)(out+e) = v;
}

extern "C" void kernel_launch(void* const* d_in, const int* in_sizes, int n_in,
                              void* d_out, int out_size, void* d_ws, size_t ws_size,
                              hipStream_t stream){
  (void)in_sizes; (void)n_in; (void)out_size; (void)ws_size;
  const float* x     = (const float*)d_in[0];
  const float* w_off = (const float*)d_in[1];
  const float* b_off = (const float*)d_in[2];
  const float* w_dcn = (const float*)d_in[3];
  const float* b_dcn = (const float*)d_in[4];
  const float* gamma1= (const float*)d_in[5];
  const float* beta1 = (const float*)d_in[6];
  const float* w_up  = (const float*)d_in[7];
  const float* gamma2= (const float*)d_in[8];
  const float* beta2 = (const float*)d_in[9];
  float* out = (float*)d_out;

  float* ws   = (float*)d_ws;
  float* om   = ws;                       // 442368
  float* xt   = om  + 442368;             // 4194304
  float* wT   = xt  + 4194304;            // 589824
  float* out1 = wT  + 589824;             // 4194304
  __hip_bfloat16* y1b  = (__hip_bfloat16*)(out1 + 4194304);     // 4194304 bf16
  __hip_bfloat16* WT2c = (__hip_bfloat16*)(out1 + 4194304 + 2097152); // 1048576 bf16
  float* st1  = out1 + 4194304 + 2097152 + 524288;   // 512
  float* st2  = st1 + 512;                            // 512

  hipMemsetAsync(om, 0, (size_t)442368*sizeof(float), stream);
  k_transpose_x <<<dim3(128,8,4), 256, 0, stream>>>(x, xt);
  k_offset_conv <<<dim3(16,4,4),  256, 0, stream>>>(x, w_off, om);
  k_build_wT    <<<2304, 256, 0, stream>>>(w_dcn, wT);
  k_build_WT2c  <<<4096, 256, 0, stream>>>(w_up, WT2c);
  k_dcn         <<<256,  256, 0, stream>>>(xt, om, b_off, wT, b_dcn, out1);
  k_bn_stats    <<<256,  256, 0, stream>>>(out1, st1, 4096);
  k_bn1_apply_t <<<dim3(128,8,4), 256, 0, stream>>>(out1, st1, gamma1, beta1, y1b);
  k_convt_mfma  <<<dim3(64,4,4),  256, 0, stream>>>(y1b, WT2c, out);
  k_bn_stats    <<<256,  256, 0, stream>>>(out, st2, 16384);
  k_bn2_apply   <<<16384,256, 0, stream>>>(out, st2, gamma2, beta2);
}

// Round 3
// 522.567 us; speedup vs baseline: 2.8674x; 1.8760x over previous
//
#include <hip/hip_runtime.h>
#include <hip/hip_bf16.h>
#include <math.h>

// Problem constants
#define B_   4
#define CIN  256
#define COUT 256
#define Hh   64
#define Ww   64
#define HW   4096   // 64*64

typedef __attribute__((ext_vector_type(8))) short short8;
typedef __attribute__((ext_vector_type(4))) float float4v;

// LDS row stride for MFMA staging buffers, in ushort (bf16) units.
// 40 ushort = 80 B: 16B-aligned, and 80*lane mod 128B has period 8 -> only
// 2-way bank aliasing on ds_read_b128 (free), vs 96 B which gives 4-way.
#define LSTR 40

__device__ __forceinline__ float sigmoidf_(float v){ return 1.0f/(1.0f+expf(-v)); }
__device__ __forceinline__ ushort f2bf(float f){
  union { float f; unsigned u; } x; x.f = f;
  unsigned r = x.u + 0x7fffu + ((x.u>>16)&1u);
  return (ushort)(r>>16);
}

// ---------- transpose x [B][C][HW] -> xt [B][HW][C] ----------
__global__ void k_transpose_x(const float* __restrict__ x, float* __restrict__ xt){
  __shared__ float ts[32][33];
  int tx = threadIdx.x & 31, ty = threadIdx.x >> 5;
  int p0 = blockIdx.x * 32, c0 = blockIdx.y * 32, b = blockIdx.z;
  const float* xb = x + (size_t)b*CIN*HW;
  float* xo = xt + (size_t)b*HW*CIN;
#pragma unroll
  for(int q=0;q<4;q++){
    int c = ty + q*8;
    ts[c][tx] = xb[(size_t)(c0+c)*HW + p0+tx];
  }
  __syncthreads();
#pragma unroll
  for(int q=0;q<4;q++){
    int pr = ty + q*8;
    xo[(size_t)(p0+pr)*CIN + c0+tx] = ts[tx][pr];
  }
}

// ---------- offset conv ----------
__global__ void k_offset_conv(const float* __restrict__ x, const float* __restrict__ w_off,
                              float* __restrict__ om){
  __shared__ float xs[18*18];
  int tid = threadIdx.x;
  int tile = blockIdx.x, cg = blockIdx.y, b = blockIdx.z;
  int ty0 = (tile>>2)*16, tx0 = (tile&3)*16;
  int ty = tid>>4, tx = tid&15;
  float acc[27];
#pragma unroll
  for(int i=0;i<27;i++) acc[i]=0.f;
  for(int c = cg*64; c < cg*64+64; ++c){
    const float* xp = x + (size_t)(b*CIN + c)*HW;
    for(int i=tid;i<324;i+=256){
      int yy = ty0 - 1 + i/18, xx = tx0 - 1 + i%18;
      float v = 0.f;
      if(yy>=0 && yy<Hh && xx>=0 && xx<Ww) v = xp[yy*Ww+xx];
      xs[i] = v;
    }
    __syncthreads();
    float nb[9];
#pragma unroll
    for(int kh=0;kh<3;kh++)
#pragma unroll
      for(int kw=0;kw<3;kw++) nb[kh*3+kw] = xs[(ty+kh)*18 + tx+kw];
    const float* wp = w_off + (size_t)c*9;
#pragma unroll
    for(int oc=0;oc<27;oc++){
      const float* wq = wp + (size_t)oc*CIN*9;
      float s = acc[oc];
#pragma unroll
      for(int k=0;k<9;k++) s = fmaf(nb[k], wq[k], s);
      acc[oc] = s;
    }
    __syncthreads();
  }
  int h = ty0+ty, w = tx0+tx;
#pragma unroll
  for(int oc=0;oc<27;oc++)
    atomicAdd(&om[(size_t)(b*27+oc)*HW + h*Ww + w], acc[oc]);
}

// ---------- weight re-layouts ----------
// Wdb[kc][o][kk] bf16; global K index = k*256 + c (tap-major); kc = k*8 + c/32, kk = c%32
__global__ void k_build_Wdb(const float* __restrict__ w_dcn, __hip_bfloat16* __restrict__ Wdb){
  int f = blockIdx.x*256 + threadIdx.x;  // grid 2304 -> 589824
  int kc = f>>13;
  int o  = (f>>5)&255;
  int kk = f&31;
  int k  = kc>>3;
  int c  = ((kc&7)<<5) | kk;
  Wdb[f] = __float2bfloat16(w_dcn[(size_t)o*2304 + c*9 + k]);
}
// WT2c[pp][kc][o][kk] bf16, K order k = ab*256 + c
__global__ void k_build_WT2c(const float* __restrict__ w_up, __hip_bfloat16* __restrict__ WT2c){
  int f = blockIdx.x*256 + threadIdx.x;    // grid 4096
  int pp = f>>18;
  int kc = (f>>13)&31;
  int o  = (f>>5)&255;
  int kk = f&31;
  int k  = kc*32 + kk;
  int ab = k>>8, c = k&255;
  int a = ab>>1, bb = ab&1;
  int ph = pp>>1, pw = pp&1;
  float v = w_up[(size_t)(c*COUT+o)*16 + (3-ph-2*a)*4 + (3-pw-2*bb)];
  WT2c[f] = __float2bfloat16(v);
}

// ---------- DCN GEMM, MFMA bf16 ----------
// grid (128 px-tiles of 32, 4 b) = 512 blocks, block 256 = 4 waves.
// Block tile: M=256 (all o), N=32 px, K=2304 (k*256+c), BK=32 -> 72 chunks.
// Wave wv: o in [wv*64, wv*64+64) x 32 px = 4x2 tiles of 16x16.
__global__ __launch_bounds__(256) void k_dcn_mfma(const float* __restrict__ xt,
                        const float* __restrict__ om, const float* __restrict__ b_off,
                        const __hip_bfloat16* __restrict__ Wdb,
                        const float* __restrict__ b_dcn, float* __restrict__ out1){
  __shared__ ushort Ws[256*LSTR];     // [o][kk]   20480 B
  __shared__ ushort Vs[32*LSTR];      // [px][kk]   2560 B
  __shared__ int    sPk[288];         // packed corner indices per (k,px)
  __shared__ float4 sCf[288];         // 4 corner coefs (mask folded in)
  int tid = threadIdx.x;
  int px0 = blockIdx.x * 32;
  int b   = blockIdx.y;

  // ---- per-(tap,px) bilinear tables ----
  for(int t=tid; t<288; t+=256){
    int k = t >> 5, px = t & 31;
    int p = px0 + px;
    int hh = p >> 6, ww = p & 63;
    const float* omp = om + (size_t)b*27*HW + p;
    float dy = omp[(size_t)k*HW]      + b_off[k];
    float dx = omp[(size_t)(9+k)*HW]  + b_off[9+k];
    float mo = sigmoidf_(omp[(size_t)(18+k)*HW] + b_off[18+k]);
    float py  = dy + (float)(hh + k/3 - 1);
    float pxf = dx + (float)(ww + k%3 - 1);
    float y0 = floorf(py), x0 = floorf(pxf);
    float wy = py - y0, wx = pxf - x0;
    float y1 = y0 + 1.0f, x1 = x0 + 1.0f;
    bool vy0 = (y0 >= 0.f) && (y0 <= 63.f);
    bool vy1 = (y1 >= 0.f) && (y1 <= 63.f);
    bool vx0 = (x0 >= 0.f) && (x0 <= 63.f);
    bool vx1 = (x1 >= 0.f) && (x1 <= 63.f);
    int iy0 = (int)fminf(fmaxf(y0,0.f),63.f);
    int iy1 = (int)fminf(fmaxf(y1,0.f),63.f);
    int ix0 = (int)fminf(fmaxf(x0,0.f),63.f);
    int ix1 = (int)fminf(fmaxf(x1,0.f),63.f);
    sPk[t] = iy0 | (iy1<<6) | (ix0<<12) | (ix1<<18);
    sCf[t] = make_float4((vy0&&vx0)? (1.f-wy)*(1.f-wx)*mo : 0.f,
                         (vy0&&vx1)? (1.f-wy)*wx*mo       : 0.f,
                         (vy1&&vx0)? wy*(1.f-wx)*mo       : 0.f,
                         (vy1&&vx1)? wy*wx*mo             : 0.f);
  }

  int lane = tid & 63, wv = tid >> 6;
  int lo = lane & 15, hi = lane >> 4;
  float4v acc[4][2];
#pragma unroll
  for(int i=0;i<4;i++)
#pragma unroll
    for(int j=0;j<2;j++) acc[i][j] = (float4v){0.f,0.f,0.f,0.f};

  int vpx  = tid >> 3;        // 0..31 pixel
  int vseg = tid & 7;         // 0..7 channel quad
  int cbase = (b*HW) << 8;    // elem offset of batch in xt

  for(int kc=0; kc<72; ++kc){
    __syncthreads();
    // stage weights: contiguous 16 KB chunk [o][kk]
    {
      const ushort* wp = (const ushort*)Wdb + ((size_t)kc<<13);
#pragma unroll
      for(int it=0; it<4; ++it){
        int g = tid + it*256;             // 8-bf16 group, 1024 groups
        uint4 v = *(const uint4*)(wp + g*8);
        *(uint4*)(&Ws[(g>>2)*LSTR + (g&3)*8]) = v;
      }
    }
    // stage vals: tap k = kc>>3, channels c0..c0+31; thread = (px, 4-ch quad)
    {
      int k = kc >> 3, c0 = (kc & 7) << 5;
      int t = (k<<5) + vpx;
      int pk = sPk[t];
      float4 cf = sCf[t];
      int coff = c0 + (vseg<<2);
      int iy0 = pk & 63, iy1 = (pk>>6)&63, ix0 = (pk>>12)&63, ix1 = (pk>>18)&63;
      const float* p00 = xt + cbase + (((iy0<<6)+ix0)<<8) + coff;
      const float* p01 = xt + cbase + (((iy0<<6)+ix1)<<8) + coff;
      const float* p10 = xt + cbase + (((iy1<<6)+ix0)<<8) + coff;
      const float* p11 = xt + cbase + (((iy1<<6)+ix1)<<8) + coff;
      float4 v00 = *(const float4*)p00;
      float4 v01 = *(const float4*)p01;
      float4 v10 = *(const float4*)p10;
      float4 v11 = *(const float4*)p11;
      union { ushort u[4]; uint2 q; } r;
      r.u[0] = f2bf(cf.x*v00.x + cf.y*v01.x + cf.z*v10.x + cf.w*v11.x);
      r.u[1] = f2bf(cf.x*v00.y + cf.y*v01.y + cf.z*v10.y + cf.w*v11.y);
      r.u[2] = f2bf(cf.x*v00.z + cf.y*v01.z + cf.z*v10.z + cf.w*v11.z);
      r.u[3] = f2bf(cf.x*v00.w + cf.y*v01.w + cf.z*v10.w + cf.w*v11.w);
      *(uint2*)(&Vs[vpx*LSTR + (vseg<<2)]) = r.q;
    }
    __syncthreads();

    const ushort* ap = &Ws[(wv*64 + lo)*LSTR + hi*8];
    const ushort* bp = &Vs[lo*LSTR + hi*8];
    short8 bfr[2];
#pragma unroll
    for(int j=0;j<2;j++) bfr[j] = *(const short8*)(bp + j*16*LSTR);
#pragma unroll
    for(int i=0;i<4;i++){
      short8 afr = *(const short8*)(ap + i*16*LSTR);
#pragma unroll
      for(int j=0;j<2;j++)
        acc[i][j] = __builtin_amdgcn_mfma_f32_16x16x32_bf16(afr, bfr[j], acc[i][j], 0,0,0);
    }
  }

  // epilogue: D row -> o, col -> px
#pragma unroll
  for(int i=0;i<4;i++){
    int ob = wv*64 + i*16 + hi*4;
#pragma unroll
    for(int r=0;r<4;r++){
      int o = ob + r;
      float bias = b_dcn[o];
      float* op = out1 + (size_t)(b*COUT + o)*HW + px0 + lo;
#pragma unroll
      for(int j=0;j<2;j++)
        op[j*16] = acc[i][j][r] + bias;
    }
  }
}

// ---------- batchnorm stats ----------
__global__ void k_bn_stats(const float* __restrict__ xin, float* __restrict__ stats, int per_b){
  int o = blockIdx.x, tid = threadIdx.x;
  float s=0.f, ss=0.f;
  for(int b=0;b<B_;b++){
    const float* p = xin + (size_t)(b*COUT+o)*per_b;
    for(int i=tid;i<per_b;i+=256){ float v = p[i]; s+=v; ss+=v*v; }
  }
  __shared__ float rs[256], rss[256];
  rs[tid]=s; rss[tid]=ss; __syncthreads();
  for(int st=128; st>0; st>>=1){
    if(tid<st){ rs[tid]+=rs[tid+st]; rss[tid]+=rss[tid+st]; }
    __syncthreads();
  }
  if(tid==0){
    float n = (float)(B_*per_b);
    float mean = rs[0]/n;
    float var  = rss[0]/n - mean*mean;
    stats[o*2] = mean; stats[o*2+1] = rsqrtf(var + 1e-5f);
  }
}

// ---------- BN1 apply + relu + transpose -> y1b bf16 [b][p][c] ----------
__global__ void k_bn1_apply_t(const float* __restrict__ out1, const float* __restrict__ stats,
                              const float* __restrict__ gamma, const float* __restrict__ beta,
                              __hip_bfloat16* __restrict__ y1b){
  __shared__ float ts[32][33];
  int tx = threadIdx.x & 31, ty = threadIdx.x >> 5;
  int p0 = blockIdx.x*32, o0 = blockIdx.y*32, b = blockIdx.z;
#pragma unroll
  for(int q=0;q<4;q++){
    int oo = ty + q*8; int o = o0 + oo;
    float m = stats[o*2], rstd = stats[o*2+1];
    float scale = rstd * gamma[o];
    float shift = beta[o] - m * scale;
    float v = out1[(size_t)(b*COUT+o)*HW + p0+tx];
    ts[oo][tx] = fmaxf(v*scale + shift, 0.f);
  }
  __syncthreads();
#pragma unroll
  for(int q=0;q<4;q++){
    int pr = ty + q*8;
    y1b[((size_t)(b*HW + p0+pr)<<8) + o0+tx] = __float2bfloat16(ts[tx][pr]);
  }
}

// ---------- conv-transpose GEMM, MFMA bf16 ----------
__global__ __launch_bounds__(256) void k_convt_mfma(const __hip_bfloat16* __restrict__ y1b,
                        const __hip_bfloat16* __restrict__ WT2c,
                        float* __restrict__ out){
  __shared__ ushort Ws[256*LSTR];
  __shared__ ushort Vs[64*LSTR];
  __shared__ int sIdx[256];
  int tid = threadIdx.x;
  int px0 = blockIdx.x * 64;
  int b   = blockIdx.y;
  int pp  = blockIdx.z;
  int ph = pp>>1, pw = pp&1;

  {
    int ab = tid>>6, px = tid&63;
    int a = ab>>1, bb = ab&1;
    int p = px0+px, r = p>>6, s = p&63;
    int ih = r + ph - 1 + a, iw = s + pw - 1 + bb;
    bool valid = (ih>=0 && ih<64 && iw>=0 && iw<64);
    sIdx[tid] = valid ? ((b*HW + ih*64+iw)<<8) : -1;
  }

  int lane = tid & 63, wv = tid >> 6;
  int lo = lane & 15, hi = lane >> 4;
  float4v acc[4][4];
#pragma unroll
  for(int i=0;i<4;i++)
#pragma unroll
    for(int j=0;j<4;j++) acc[i][j] = (float4v){0.f,0.f,0.f,0.f};

  int vpx = tid >> 2, vseg = tid & 3;
  const ushort* wbase = (const ushort*)WT2c + ((size_t)pp<<18);
  const ushort* ysrc  = (const ushort*)y1b;

  for(int kc=0; kc<32; ++kc){
    __syncthreads();
    {
      const ushort* wp = wbase + (kc<<13);
#pragma unroll
      for(int it=0; it<4; ++it){
        int g = tid + it*256;
        uint4 v = *(const uint4*)(wp + g*8);
        *(uint4*)(&Ws[(g>>2)*LSTR + (g&3)*8]) = v;
      }
    }
    {
      int ab = kc>>3, c0 = (kc&7)<<5;
      int idx = sIdx[(ab<<6) + vpx];
      uint4 v = make_uint4(0u,0u,0u,0u);
      if(idx >= 0) v = *(const uint4*)(ysrc + idx + c0 + vseg*8);
      *(uint4*)(&Vs[vpx*LSTR + vseg*8]) = v;
    }
    __syncthreads();

    const ushort* ap = &Ws[(wv*64 + lo)*LSTR + hi*8];
    const ushort* bp = &Vs[lo*LSTR + hi*8];
    short8 bfr[4];
#pragma unroll
    for(int j=0;j<4;j++) bfr[j] = *(const short8*)(bp + j*16*LSTR);
#pragma unroll
    for(int i=0;i<4;i++){
      short8 afr = *(const short8*)(ap + i*16*LSTR);
#pragma unroll
      for(int j=0;j<4;j++)
        acc[i][j] = __builtin_amdgcn_mfma_f32_16x16x32_bf16(afr, bfr[j], acc[i][j], 0,0,0);
    }
  }

#pragma unroll
  for(int i=0;i<4;i++){
    int ob = wv*64 + i*16 + hi*4;
#pragma unroll
    for(int r=0;r<4;r++){
      float* op = out + (((size_t)(b*COUT + ob + r))<<14);
#pragma unroll
      for(int j=0;j<4;j++){
        int p = px0 + j*16 + lo;
        int rr = p>>6, ss = p&63;
        op[(2*rr+ph)*128 + (2*ss+pw)] = acc[i][j][r];
      }
    }
  }
}

// ---------- BN2 apply + relu ----------
__global__ void k_bn2_apply(float* __restrict__ out, const float* __restrict__ stats,
                            const float* __restrict__ gamma, const float* __restrict__ beta){
  size_t gid = (size_t)blockIdx.x*256 + threadIdx.x;
  size_t e = gid*4;
  int o = (int)((e >> 14) & 255);
  float m = stats[o*2], rstd = stats[o*2+1];
  float scale = rstd * gamma[o];
  float shift = beta[o] - m * scale;
  float4 v = *(float4*)(out+e);
  v.x = fmaxf(v.x*scale + shift, 0.f);
  v.y = fmaxf(v.y*scale + shift, 0.f);
  v.z = fmaxf(v.z*scale + shift, 0.f);
  v.w = fmaxf(v.w*scale + shift, 0.f);
  *(float4*)(out+e) = v;
}

extern "C" void kernel_launch(void* const* d_in, const int* in_sizes, int n_in,
                              void* d_out, int out_size, void* d_ws, size_t ws_size,
                              hipStream_t stream){
  (void)in_sizes; (void)n_in; (void)out_size; (void)ws_size;
  const float* x     = (const float*)d_in[0];
  const float* w_off = (const float*)d_in[1];
  const float* b_off = (const float*)d_in[2];
  const float* w_dcn = (const float*)d_in[3];
  const float* b_dcn = (const float*)d_in[4];
  const float* gamma1= (const float*)d_in[5];
  const float* beta1 = (const float*)d_in[6];
  const float* w_up  = (const float*)d_in[7];
  const float* gamma2= (const float*)d_in[8];
  const float* beta2 = (const float*)d_in[9];
  float* out = (float*)d_out;

  float* ws   = (float*)d_ws;
  float* om   = ws;                        // 442368
  float* xt   = om  + 442368;              // 4194304
  float* out1 = xt  + 4194304;             // 4194304
  __hip_bfloat16* y1b  = (__hip_bfloat16*)(out1 + 4194304);            // 4194304 bf16
  __hip_bfloat16* WT2c = (__hip_bfloat16*)(out1 + 4194304 + 2097152);  // 1048576 bf16
  __hip_bfloat16* Wdb  = (__hip_bfloat16*)(out1 + 4194304 + 2097152 + 524288); // 589824 bf16
  float* st1  = out1 + 4194304 + 2097152 + 524288 + 294912;  // 512
  float* st2  = st1 + 512;                                   // 512

  hipMemsetAsync(om, 0, (size_t)442368*sizeof(float), stream);
  k_transpose_x <<<dim3(128,8,4), 256, 0, stream>>>(x, xt);
  k_offset_conv <<<dim3(16,4,4),  256, 0, stream>>>(x, w_off, om);
  k_build_Wdb   <<<2304, 256, 0, stream>>>(w_dcn, Wdb);
  k_build_WT2c  <<<4096, 256, 0, stream>>>(w_up, WT2c);
  k_dcn_mfma    <<<dim3(128,4),   256, 0, stream>>>(xt, om, b_off, Wdb, b_dcn, out1);
  k_bn_stats    <<<256,  256, 0, stream>>>(out1, st1, 4096);
  k_bn1_apply_t <<<dim3(128,8,4), 256, 0, stream>>>(out1, st1, gamma1, beta1, y1b);
  k_convt_mfma  <<<dim3(64,4,4),  256, 0, stream>>>(y1b, WT2c, out);
  k_bn_stats    <<<256,  256, 0, stream>>>(out, st2, 16384);
  k_bn2_apply   <<<16384,256, 0, stream>>>(out, st2, gamma2, beta2);
}

// Round 4
// 412.886 us; speedup vs baseline: 3.6291x; 1.2656x over previous
//
#include <hip/hip_runtime.h>
#include <hip/hip_bf16.h>
#include <math.h>

// Problem constants
#define B_   4
#define CIN  256
#define COUT 256
#define Hh   64
#define Ww   64
#define HW   4096   // 64*64

typedef __attribute__((ext_vector_type(8))) short short8;
typedef __attribute__((ext_vector_type(4))) float float4v;

// LDS row stride for MFMA staging buffers, in ushort (bf16) units.
// 40 ushort = 80 B: 16B-aligned, and 80*lane mod 128B has period 8 -> only
// 2-way bank aliasing on ds_read_b128 (free), vs 96 B which gives 4-way.
#define LSTR 40

__device__ __forceinline__ float sigmoidf_(float v){ return 1.0f/(1.0f+expf(-v)); }
__device__ __forceinline__ ushort f2bf(float f){
  union { float f; unsigned u; } x; x.f = f;
  unsigned r = x.u + 0x7fffu + ((x.u>>16)&1u);
  return (ushort)(r>>16);
}

// ---------- transpose x [B][C][HW] -> xt [B][HW][C] ----------
__global__ void k_transpose_x(const float* __restrict__ x, float* __restrict__ xt){
  __shared__ float ts[32][33];
  int tx = threadIdx.x & 31, ty = threadIdx.x >> 5;
  int p0 = blockIdx.x * 32, c0 = blockIdx.y * 32, b = blockIdx.z;
  const float* xb = x + (size_t)b*CIN*HW;
  float* xo = xt + (size_t)b*HW*CIN;
#pragma unroll
  for(int q=0;q<4;q++){
    int c = ty + q*8;
    ts[c][tx] = xb[(size_t)(c0+c)*HW + p0+tx];
  }
  __syncthreads();
#pragma unroll
  for(int q=0;q<4;q++){
    int pr = ty + q*8;
    xo[(size_t)(p0+pr)*CIN + c0+tx] = ts[tx][pr];
  }
}

// ---------- weight re-layouts ----------
// Wob[kc][o32][kk] bf16 for offset conv; K = tap*256 + c (tap-major), M padded 27->32
__global__ void k_build_Wob(const float* __restrict__ w_off, __hip_bfloat16* __restrict__ Wob){
  int f = blockIdx.x*256 + threadIdx.x;   // grid 288 -> 73728
  int kc = f>>10;
  int o  = (f>>5)&31;
  int kk = f&31;
  int k  = kc*32 + kk;
  int tap = k>>8, c = k&255;
  float v = (o < 27) ? w_off[(size_t)o*2304 + c*9 + tap] : 0.f;
  Wob[f] = __float2bfloat16(v);
}
// Wdb[kc][o][kk] bf16; global K index = k*256 + c (tap-major); kc = k*8 + c/32, kk = c%32
__global__ void k_build_Wdb(const float* __restrict__ w_dcn, __hip_bfloat16* __restrict__ Wdb){
  int f = blockIdx.x*256 + threadIdx.x;  // grid 2304 -> 589824
  int kc = f>>13;
  int o  = (f>>5)&255;
  int kk = f&31;
  int k  = kc>>3;
  int c  = ((kc&7)<<5) | kk;
  Wdb[f] = __float2bfloat16(w_dcn[(size_t)o*2304 + c*9 + k]);
}
// WT2c[pp][kc][o][kk] bf16, K order k = ab*256 + c
__global__ void k_build_WT2c(const float* __restrict__ w_up, __hip_bfloat16* __restrict__ WT2c){
  int f = blockIdx.x*256 + threadIdx.x;    // grid 4096
  int pp = f>>18;
  int kc = (f>>13)&31;
  int o  = (f>>5)&255;
  int kk = f&31;
  int k  = kc*32 + kk;
  int ab = k>>8, c = k&255;
  int a = ab>>1, bb = ab&1;
  int ph = pp>>1, pw = pp&1;
  float v = w_up[(size_t)(c*COUT+o)*16 + (3-ph-2*a)*4 + (3-pw-2*bb)];
  WT2c[f] = __float2bfloat16(v);
}

// ---------- offset conv as MFMA GEMM ----------
// om[b][o<27][p] = sum_{c,tap} w_off[o][c][tap] * x[b][c][p+off(tap)]
// grid (128 px-tiles of 32, 4 b) = 512 blocks, block 256 = 4 waves.
// Block tile: M=32 (27 taps padded), N=32 px, K=2304, BK=32 -> 72 chunks.
// Wave wv owns one 16x16 tile: mi=wv>>1, ni=wv&1.
__global__ __launch_bounds__(256) void k_offset_mfma(const float* __restrict__ xt,
                        const __hip_bfloat16* __restrict__ Wob, float* __restrict__ om){
  __shared__ ushort Ws[32*LSTR];
  __shared__ ushort Vs[32*LSTR];
  __shared__ int sIdx[288];        // [tap][px] elem offset into xt, or -1
  int tid = threadIdx.x;
  int px0 = blockIdx.x * 32;
  int b   = blockIdx.y;

  for(int t=tid; t<288; t+=256){
    int tap = t >> 5, px = t & 31;
    int p = px0 + px, hh = p>>6, ww = p&63;
    int ih = hh + tap/3 - 1, iw = ww + tap%3 - 1;
    bool valid = (ih>=0 && ih<64 && iw>=0 && iw<64);
    sIdx[t] = valid ? ((b*HW + ih*64+iw)<<8) : -1;
  }

  int lane = tid & 63, wv = tid >> 6;
  int lo = lane & 15, hi = lane >> 4;
  int mi = wv >> 1, ni = wv & 1;
  float4v acc = (float4v){0.f,0.f,0.f,0.f};

  int vpx = tid >> 3, vseg = tid & 7;

  for(int kc=0; kc<72; ++kc){
    __syncthreads();
    // stage weights: 2 KB chunk [o32][kk]
    if(tid < 128){
      const ushort* wp = (const ushort*)Wob + ((size_t)kc<<10);
      uint4 v = *(const uint4*)(wp + tid*8);
      *(uint4*)(&Ws[(tid>>2)*LSTR + (tid&3)*8]) = v;
    }
    // stage vals: tap = kc>>3, channels c0..c0+31; thread = (px, 4-ch quad)
    {
      int tap = kc >> 3, c0 = (kc & 7) << 5;
      int idx = sIdx[(tap<<5) + vpx];
      union { ushort u[4]; uint2 q; } r;
      if(idx >= 0){
        float4 v = *(const float4*)(xt + idx + c0 + (vseg<<2));
        r.u[0] = f2bf(v.x); r.u[1] = f2bf(v.y); r.u[2] = f2bf(v.z); r.u[3] = f2bf(v.w);
      } else {
        r.q = make_uint2(0u,0u);
      }
      *(uint2*)(&Vs[vpx*LSTR + (vseg<<2)]) = r.q;
    }
    __syncthreads();

    short8 afr = *(const short8*)(&Ws[(mi*16 + lo)*LSTR + hi*8]);
    short8 bfr = *(const short8*)(&Vs[(ni*16 + lo)*LSTR + hi*8]);
    acc = __builtin_amdgcn_mfma_f32_16x16x32_bf16(afr, bfr, acc, 0,0,0);
  }

  // epilogue: row=(hi*4+r) -> o, col=lo -> px
  int ob = mi*16 + hi*4;
  int p  = px0 + ni*16 + lo;
#pragma unroll
  for(int r=0;r<4;r++){
    int o = ob + r;
    if(o < 27) om[(size_t)(b*27+o)*HW + p] = acc[r];
  }
}

// ---------- DCN GEMM, MFMA bf16 ----------
// grid (128 px-tiles of 32, 4 b) = 512 blocks, block 256 = 4 waves.
// Block tile: M=256 (all o), N=32 px, K=2304 (k*256+c), BK=32 -> 72 chunks.
__global__ __launch_bounds__(256) void k_dcn_mfma(const float* __restrict__ xt,
                        const float* __restrict__ om, const float* __restrict__ b_off,
                        const __hip_bfloat16* __restrict__ Wdb,
                        const float* __restrict__ b_dcn, float* __restrict__ out1){
  __shared__ ushort Ws[256*LSTR];     // [o][kk]   20480 B
  __shared__ ushort Vs[32*LSTR];      // [px][kk]   2560 B
  __shared__ int    sPk[288];         // packed corner indices per (k,px)
  __shared__ float4 sCf[288];         // 4 corner coefs (mask folded in)
  int tid = threadIdx.x;
  int px0 = blockIdx.x * 32;
  int b   = blockIdx.y;

  for(int t=tid; t<288; t+=256){
    int k = t >> 5, px = t & 31;
    int p = px0 + px;
    int hh = p >> 6, ww = p & 63;
    const float* omp = om + (size_t)b*27*HW + p;
    float dy = omp[(size_t)k*HW]      + b_off[k];
    float dx = omp[(size_t)(9+k)*HW]  + b_off[9+k];
    float mo = sigmoidf_(omp[(size_t)(18+k)*HW] + b_off[18+k]);
    float py  = dy + (float)(hh + k/3 - 1);
    float pxf = dx + (float)(ww + k%3 - 1);
    float y0 = floorf(py), x0 = floorf(pxf);
    float wy = py - y0, wx = pxf - x0;
    float y1 = y0 + 1.0f, x1 = x0 + 1.0f;
    bool vy0 = (y0 >= 0.f) && (y0 <= 63.f);
    bool vy1 = (y1 >= 0.f) && (y1 <= 63.f);
    bool vx0 = (x0 >= 0.f) && (x0 <= 63.f);
    bool vx1 = (x1 >= 0.f) && (x1 <= 63.f);
    int iy0 = (int)fminf(fmaxf(y0,0.f),63.f);
    int iy1 = (int)fminf(fmaxf(y1,0.f),63.f);
    int ix0 = (int)fminf(fmaxf(x0,0.f),63.f);
    int ix1 = (int)fminf(fmaxf(x1,0.f),63.f);
    sPk[t] = iy0 | (iy1<<6) | (ix0<<12) | (ix1<<18);
    sCf[t] = make_float4((vy0&&vx0)? (1.f-wy)*(1.f-wx)*mo : 0.f,
                         (vy0&&vx1)? (1.f-wy)*wx*mo       : 0.f,
                         (vy1&&vx0)? wy*(1.f-wx)*mo       : 0.f,
                         (vy1&&vx1)? wy*wx*mo             : 0.f);
  }

  int lane = tid & 63, wv = tid >> 6;
  int lo = lane & 15, hi = lane >> 4;
  float4v acc[4][2];
#pragma unroll
  for(int i=0;i<4;i++)
#pragma unroll
    for(int j=0;j<2;j++) acc[i][j] = (float4v){0.f,0.f,0.f,0.f};

  int vpx  = tid >> 3;
  int vseg = tid & 7;
  int cbase = (b*HW) << 8;

  for(int kc=0; kc<72; ++kc){
    __syncthreads();
    {
      const ushort* wp = (const ushort*)Wdb + ((size_t)kc<<13);
#pragma unroll
      for(int it=0; it<4; ++it){
        int g = tid + it*256;
        uint4 v = *(const uint4*)(wp + g*8);
        *(uint4*)(&Ws[(g>>2)*LSTR + (g&3)*8]) = v;
      }
    }
    {
      int k = kc >> 3, c0 = (kc & 7) << 5;
      int t = (k<<5) + vpx;
      int pk = sPk[t];
      float4 cf = sCf[t];
      int coff = c0 + (vseg<<2);
      int iy0 = pk & 63, iy1 = (pk>>6)&63, ix0 = (pk>>12)&63, ix1 = (pk>>18)&63;
      float4 v00 = *(const float4*)(xt + cbase + (((iy0<<6)+ix0)<<8) + coff);
      float4 v01 = *(const float4*)(xt + cbase + (((iy0<<6)+ix1)<<8) + coff);
      float4 v10 = *(const float4*)(xt + cbase + (((iy1<<6)+ix0)<<8) + coff);
      float4 v11 = *(const float4*)(xt + cbase + (((iy1<<6)+ix1)<<8) + coff);
      union { ushort u[4]; uint2 q; } r;
      r.u[0] = f2bf(cf.x*v00.x + cf.y*v01.x + cf.z*v10.x + cf.w*v11.x);
      r.u[1] = f2bf(cf.x*v00.y + cf.y*v01.y + cf.z*v10.y + cf.w*v11.y);
      r.u[2] = f2bf(cf.x*v00.z + cf.y*v01.z + cf.z*v10.z + cf.w*v11.z);
      r.u[3] = f2bf(cf.x*v00.w + cf.y*v01.w + cf.z*v10.w + cf.w*v11.w);
      *(uint2*)(&Vs[vpx*LSTR + (vseg<<2)]) = r.q;
    }
    __syncthreads();

    const ushort* ap = &Ws[(wv*64 + lo)*LSTR + hi*8];
    const ushort* bp = &Vs[lo*LSTR + hi*8];
    short8 bfr[2];
#pragma unroll
    for(int j=0;j<2;j++) bfr[j] = *(const short8*)(bp + j*16*LSTR);
#pragma unroll
    for(int i=0;i<4;i++){
      short8 afr = *(const short8*)(ap + i*16*LSTR);
#pragma unroll
      for(int j=0;j<2;j++)
        acc[i][j] = __builtin_amdgcn_mfma_f32_16x16x32_bf16(afr, bfr[j], acc[i][j], 0,0,0);
    }
  }

#pragma unroll
  for(int i=0;i<4;i++){
    int ob = wv*64 + i*16 + hi*4;
#pragma unroll
    for(int r=0;r<4;r++){
      int o = ob + r;
      float bias = b_dcn[o];
      float* op = out1 + (size_t)(b*COUT + o)*HW + px0 + lo;
#pragma unroll
      for(int j=0;j<2;j++)
        op[j*16] = acc[i][j][r] + bias;
    }
  }
}

// ---------- batchnorm stats ----------
__global__ void k_bn_stats(const float* __restrict__ xin, float* __restrict__ stats, int per_b){
  int o = blockIdx.x, tid = threadIdx.x;
  float s=0.f, ss=0.f;
  for(int b=0;b<B_;b++){
    const float* p = xin + (size_t)(b*COUT+o)*per_b;
    for(int i=tid;i<per_b;i+=256){ float v = p[i]; s+=v; ss+=v*v; }
  }
  __shared__ float rs[256], rss[256];
  rs[tid]=s; rss[tid]=ss; __syncthreads();
  for(int st=128; st>0; st>>=1){
    if(tid<st){ rs[tid]+=rs[tid+st]; rss[tid]+=rss[tid+st]; }
    __syncthreads();
  }
  if(tid==0){
    float n = (float)(B_*per_b);
    float mean = rs[0]/n;
    float var  = rss[0]/n - mean*mean;
    stats[o*2] = mean; stats[o*2+1] = rsqrtf(var + 1e-5f);
  }
}

// ---------- BN1 apply + relu + transpose -> y1b bf16 [b][p][c] ----------
__global__ void k_bn1_apply_t(const float* __restrict__ out1, const float* __restrict__ stats,
                              const float* __restrict__ gamma, const float* __restrict__ beta,
                              __hip_bfloat16* __restrict__ y1b){
  __shared__ float ts[32][33];
  int tx = threadIdx.x & 31, ty = threadIdx.x >> 5;
  int p0 = blockIdx.x*32, o0 = blockIdx.y*32, b = blockIdx.z;
#pragma unroll
  for(int q=0;q<4;q++){
    int oo = ty + q*8; int o = o0 + oo;
    float m = stats[o*2], rstd = stats[o*2+1];
    float scale = rstd * gamma[o];
    float shift = beta[o] - m * scale;
    float v = out1[(size_t)(b*COUT+o)*HW + p0+tx];
    ts[oo][tx] = fmaxf(v*scale + shift, 0.f);
  }
  __syncthreads();
#pragma unroll
  for(int q=0;q<4;q++){
    int pr = ty + q*8;
    y1b[((size_t)(b*HW + p0+pr)<<8) + o0+tx] = __float2bfloat16(ts[tx][pr]);
  }
}

// ---------- conv-transpose GEMM, MFMA bf16 ----------
__global__ __launch_bounds__(256) void k_convt_mfma(const __hip_bfloat16* __restrict__ y1b,
                        const __hip_bfloat16* __restrict__ WT2c,
                        float* __restrict__ out){
  __shared__ ushort Ws[256*LSTR];
  __shared__ ushort Vs[64*LSTR];
  __shared__ int sIdx[256];
  int tid = threadIdx.x;
  int px0 = blockIdx.x * 64;
  int b   = blockIdx.y;
  int pp  = blockIdx.z;
  int ph = pp>>1, pw = pp&1;

  {
    int ab = tid>>6, px = tid&63;
    int a = ab>>1, bb = ab&1;
    int p = px0+px, r = p>>6, s = p&63;
    int ih = r + ph - 1 + a, iw = s + pw - 1 + bb;
    bool valid = (ih>=0 && ih<64 && iw>=0 && iw<64);
    sIdx[tid] = valid ? ((b*HW + ih*64+iw)<<8) : -1;
  }

  int lane = tid & 63, wv = tid >> 6;
  int lo = lane & 15, hi = lane >> 4;
  float4v acc[4][4];
#pragma unroll
  for(int i=0;i<4;i++)
#pragma unroll
    for(int j=0;j<4;j++) acc[i][j] = (float4v){0.f,0.f,0.f,0.f};

  int vpx = tid >> 2, vseg = tid & 3;
  const ushort* wbase = (const ushort*)WT2c + ((size_t)pp<<18);
  const ushort* ysrc  = (const ushort*)y1b;

  for(int kc=0; kc<32; ++kc){
    __syncthreads();
    {
      const ushort* wp = wbase + (kc<<13);
#pragma unroll
      for(int it=0; it<4; ++it){
        int g = tid + it*256;
        uint4 v = *(const uint4*)(wp + g*8);
        *(uint4*)(&Ws[(g>>2)*LSTR + (g&3)*8]) = v;
      }
    }
    {
      int ab = kc>>3, c0 = (kc&7)<<5;
      int idx = sIdx[(ab<<6) + vpx];
      uint4 v = make_uint4(0u,0u,0u,0u);
      if(idx >= 0) v = *(const uint4*)(ysrc + idx + c0 + vseg*8);
      *(uint4*)(&Vs[vpx*LSTR + vseg*8]) = v;
    }
    __syncthreads();

    const ushort* ap = &Ws[(wv*64 + lo)*LSTR + hi*8];
    const ushort* bp = &Vs[lo*LSTR + hi*8];
    short8 bfr[4];
#pragma unroll
    for(int j=0;j<4;j++) bfr[j] = *(const short8*)(bp + j*16*LSTR);
#pragma unroll
    for(int i=0;i<4;i++){
      short8 afr = *(const short8*)(ap + i*16*LSTR);
#pragma unroll
      for(int j=0;j<4;j++)
        acc[i][j] = __builtin_amdgcn_mfma_f32_16x16x32_bf16(afr, bfr[j], acc[i][j], 0,0,0);
    }
  }

#pragma unroll
  for(int i=0;i<4;i++){
    int ob = wv*64 + i*16 + hi*4;
#pragma unroll
    for(int r=0;r<4;r++){
      float* op = out + (((size_t)(b*COUT + ob + r))<<14);
#pragma unroll
      for(int j=0;j<4;j++){
        int p = px0 + j*16 + lo;
        int rr = p>>6, ss = p&63;
        op[(2*rr+ph)*128 + (2*ss+pw)] = acc[i][j][r];
      }
    }
  }
}

// ---------- BN2 apply + relu ----------
__global__ void k_bn2_apply(float* __restrict__ out, const float* __restrict__ stats,
                            const float* __restrict__ gamma, const float* __restrict__ beta){
  size_t gid = (size_t)blockIdx.x*256 + threadIdx.x;
  size_t e = gid*4;
  int o = (int)((e >> 14) & 255);
  float m = stats[o*2], rstd = stats[o*2+1];
  float scale = rstd * gamma[o];
  float shift = beta[o] - m * scale;
  float4 v = *(float4*)(out+e);
  v.x = fmaxf(v.x*scale + shift, 0.f);
  v.y = fmaxf(v.y*scale + shift, 0.f);
  v.z = fmaxf(v.z*scale + shift, 0.f);
  v.w = fmaxf(v.w*scale + shift, 0.f);
  *(float4*)(out+e) = v;
}

extern "C" void kernel_launch(void* const* d_in, const int* in_sizes, int n_in,
                              void* d_out, int out_size, void* d_ws, size_t ws_size,
                              hipStream_t stream){
  (void)in_sizes; (void)n_in; (void)out_size; (void)ws_size;
  const float* x     = (const float*)d_in[0];
  const float* w_off = (const float*)d_in[1];
  const float* b_off = (const float*)d_in[2];
  const float* w_dcn = (const float*)d_in[3];
  const float* b_dcn = (const float*)d_in[4];
  const float* gamma1= (const float*)d_in[5];
  const float* beta1 = (const float*)d_in[6];
  const float* w_up  = (const float*)d_in[7];
  const float* gamma2= (const float*)d_in[8];
  const float* beta2 = (const float*)d_in[9];
  float* out = (float*)d_out;

  float* ws   = (float*)d_ws;
  float* om   = ws;                        // 442368
  float* xt   = om  + 442368;              // 4194304
  float* out1 = xt  + 4194304;             // 4194304
  __hip_bfloat16* y1b  = (__hip_bfloat16*)(out1 + 4194304);            // 4194304 bf16
  __hip_bfloat16* WT2c = (__hip_bfloat16*)(out1 + 4194304 + 2097152);  // 1048576 bf16
  __hip_bfloat16* Wdb  = (__hip_bfloat16*)(out1 + 4194304 + 2097152 + 524288); // 589824 bf16
  __hip_bfloat16* Wob  = (__hip_bfloat16*)(out1 + 4194304 + 2097152 + 524288 + 294912); // 73728 bf16
  float* st1  = out1 + 4194304 + 2097152 + 524288 + 294912 + 36864;  // 512
  float* st2  = st1 + 512;                                           // 512

  k_transpose_x <<<dim3(128,8,4), 256, 0, stream>>>(x, xt);
  k_build_Wob   <<<288,  256, 0, stream>>>(w_off, Wob);
  k_build_Wdb   <<<2304, 256, 0, stream>>>(w_dcn, Wdb);
  k_build_WT2c  <<<4096, 256, 0, stream>>>(w_up, WT2c);
  k_offset_mfma <<<dim3(128,4),   256, 0, stream>>>(xt, Wob, om);
  k_dcn_mfma    <<<dim3(128,4),   256, 0, stream>>>(xt, om, b_off, Wdb, b_dcn, out1);
  k_bn_stats    <<<256,  256, 0, stream>>>(out1, st1, 4096);
  k_bn1_apply_t <<<dim3(128,8,4), 256, 0, stream>>>(out1, st1, gamma1, beta1, y1b);
  k_convt_mfma  <<<dim3(64,4,4),  256, 0, stream>>>(y1b, WT2c, out);
  k_bn_stats    <<<256,  256, 0, stream>>>(out, st2, 16384);
  k_bn2_apply   <<<16384,256, 0, stream>>>(out, st2, gamma2, beta2);
}

// Round 5
// 360.987 us; speedup vs baseline: 4.1509x; 1.1438x over previous
//
#include <hip/hip_runtime.h>
#include <hip/hip_bf16.h>
#include <math.h>

// Problem constants
#define B_   4
#define CIN  256
#define COUT 256
#define HW   4096   // 64*64

typedef __attribute__((ext_vector_type(8))) short short8;
typedef __attribute__((ext_vector_type(4))) float float4v;

// LDS row stride (ushorts). 80 B: 16B-aligned, period-8 bank pattern -> 2-way (free).
#define LSTR 40

__device__ __forceinline__ float sigmoidf_(float v){ return 1.0f/(1.0f+expf(-v)); }
__device__ __forceinline__ ushort f2bf(float f){
  union { float f; unsigned u; } x; x.f = f;
  unsigned r = x.u + 0x7fffu + ((x.u>>16)&1u);
  return (ushort)(r>>16);
}
__device__ __forceinline__ float bflo(unsigned u){ union{unsigned u; float f;} c; c.u = u<<16;          return c.f; }
__device__ __forceinline__ float bfhi(unsigned u){ union{unsigned u; float f;} c; c.u = u & 0xffff0000u; return c.f; }

// ---------- transpose x [B][C][HW] -> xtb [B][HW][C] bf16 ----------
__global__ void k_transpose_x(const float* __restrict__ x, ushort* __restrict__ xtb){
  __shared__ float ts[32][33];
  int tx = threadIdx.x & 31, ty = threadIdx.x >> 5;
  int p0 = blockIdx.x * 32, c0 = blockIdx.y * 32, b = blockIdx.z;
  const float* xb = x + (size_t)b*CIN*HW;
#pragma unroll
  for(int q=0;q<4;q++){
    int c = ty + q*8;
    ts[c][tx] = xb[(size_t)(c0+c)*HW + p0+tx];
  }
  __syncthreads();
#pragma unroll
  for(int q=0;q<4;q++){
    int pr = ty + q*8;
    xtb[((size_t)(b*HW + p0+pr)<<8) + c0+tx] = f2bf(ts[tx][pr]);
  }
}

// ---------- weight re-layouts (bf16, K-chunked [kc][o][kk]) ----------
__global__ void k_build_Wob(const float* __restrict__ w_off, ushort* __restrict__ Wob){
  int f = blockIdx.x*256 + threadIdx.x;   // grid 288
  int kc = f>>10, o = (f>>5)&31, kk = f&31;
  int k = kc*32 + kk, tap = k>>8, c = k&255;
  float v = (o < 27) ? w_off[(size_t)o*2304 + c*9 + tap] : 0.f;
  Wob[f] = f2bf(v);
}
__global__ void k_build_Wdb(const float* __restrict__ w_dcn, ushort* __restrict__ Wdb){
  int f = blockIdx.x*256 + threadIdx.x;  // grid 2304
  int kc = f>>13, o = (f>>5)&255, kk = f&31;
  int k = kc>>3, c = ((kc&7)<<5) | kk;
  Wdb[f] = f2bf(w_dcn[(size_t)o*2304 + c*9 + k]);
}
__global__ void k_build_WT2c(const float* __restrict__ w_up, ushort* __restrict__ WT2c){
  int f = blockIdx.x*256 + threadIdx.x;    // grid 4096
  int pp = f>>18, kc = (f>>13)&31, o = (f>>5)&255, kk = f&31;
  int k = kc*32 + kk, ab = k>>8, c = k&255;
  int a = ab>>1, bb = ab&1, ph = pp>>1, pw = pp&1;
  WT2c[f] = f2bf(w_up[(size_t)(c*COUT+o)*16 + (3-ph-2*a)*4 + (3-pw-2*bb)]);
}

// ---------- offset conv MFMA: M=32(27), Nb=64 px, K=2304, reg-prefetch pipeline ----------
// grid (64,4) = 256 blocks, 256 thr = 4 waves; wave wv owns px quarter, 2 m-tiles.
__global__ __launch_bounds__(256) void k_offset_mfma(const ushort* __restrict__ xtb,
                        const ushort* __restrict__ Wob, float* __restrict__ om){
  __shared__ ushort Ws[32*LSTR];
  __shared__ ushort Vs[64*LSTR];
  __shared__ int sIdx[576];
  int tid = threadIdx.x;
  int px0 = blockIdx.x * 64;
  int b   = blockIdx.y;
  for(int t=tid; t<576; t+=256){
    int tap = t>>6, px = t&63;
    int p = px0+px, hh = p>>6, ww = p&63;
    int ih = hh + tap/3 - 1, iw = ww + tap%3 - 1;
    sIdx[t] = (ih>=0 && ih<64 && iw>=0 && iw<64) ? ((b*HW + ih*64+iw)<<8) : -1;
  }
  __syncthreads();

  int lane = tid&63, wv = tid>>6, lo = lane&15, hi = lane>>4;
  float4v acc[2];
  acc[0] = acc[1] = (float4v){0.f,0.f,0.f,0.f};
  int vpx = tid>>2, vseg = tid&3;

  uint4 wpre = make_uint4(0,0,0,0), vpre = make_uint4(0,0,0,0);
  { // prefetch kc=0
    if(tid < 128) wpre = *(const uint4*)(Wob + tid*8);
    int idx = sIdx[vpx];
    if(idx >= 0) vpre = *(const uint4*)(xtb + idx + (vseg<<3));
  }
#pragma unroll 1
  for(int kc=0; kc<72; ++kc){
    if(tid < 128) *(uint4*)(&Ws[(tid>>2)*LSTR + (tid&3)*8]) = wpre;
    *(uint4*)(&Vs[vpx*LSTR + (vseg<<3)]) = vpre;
    __syncthreads();
    int kn = kc<71 ? kc+1 : kc;
    {
      if(tid < 128) wpre = *(const uint4*)(Wob + ((size_t)kn<<10) + tid*8);
      int tap = kn>>3, c0 = (kn&7)<<5;
      int idx = sIdx[(tap<<6) + vpx];
      vpre = make_uint4(0,0,0,0);
      if(idx >= 0) vpre = *(const uint4*)(xtb + idx + c0 + (vseg<<3));
    }
    short8 bfr = *(const short8*)(&Vs[(wv*16+lo)*LSTR + hi*8]);
#pragma unroll
    for(int mi=0;mi<2;mi++){
      short8 afr = *(const short8*)(&Ws[(mi*16+lo)*LSTR + hi*8]);
      acc[mi] = __builtin_amdgcn_mfma_f32_16x16x32_bf16(afr, bfr, acc[mi], 0,0,0);
    }
    __syncthreads();
  }
  int p = px0 + wv*16 + lo;
#pragma unroll
  for(int mi=0;mi<2;mi++){
    int ob = mi*16 + hi*4;
#pragma unroll
    for(int r=0;r<4;r++){
      int o = ob + r;
      if(o < 27) om[(size_t)(b*27+o)*HW + p] = acc[mi][r];
    }
  }
}

// ---------- DCN MFMA: Mb=256, Nb=64, K=2304, fused bilinear gather, reg-prefetch ----------
// grid (64,4) = 256 blocks, 256 thr = 4 waves; wave wv owns o in [wv*64, wv*64+64) x 64 px.
__global__ __launch_bounds__(256) void k_dcn_mfma(const ushort* __restrict__ xtb,
                        const float* __restrict__ om, const float* __restrict__ b_off,
                        const ushort* __restrict__ Wdb,
                        const float* __restrict__ b_dcn, float* __restrict__ out1){
  __shared__ ushort Ws[256*LSTR];
  __shared__ ushort Vs[64*LSTR];
  __shared__ int    sPk[576];
  __shared__ float4 sCf[576];
  int tid = threadIdx.x;
  int px0 = blockIdx.x * 64;
  int b   = blockIdx.y;

  for(int t=tid; t<576; t+=256){
    int k = t>>6, px = t&63;
    int p = px0 + px, hh = p>>6, ww = p&63;
    const float* omp = om + (size_t)b*27*HW + p;
    float dy = omp[(size_t)k*HW]      + b_off[k];
    float dx = omp[(size_t)(9+k)*HW]  + b_off[9+k];
    float mo = sigmoidf_(omp[(size_t)(18+k)*HW] + b_off[18+k]);
    float py  = dy + (float)(hh + k/3 - 1);
    float pxf = dx + (float)(ww + k%3 - 1);
    float y0 = floorf(py), x0 = floorf(pxf);
    float wy = py - y0, wx = pxf - x0;
    float y1 = y0 + 1.0f, x1 = x0 + 1.0f;
    bool vy0 = (y0>=0.f)&&(y0<=63.f), vy1 = (y1>=0.f)&&(y1<=63.f);
    bool vx0 = (x0>=0.f)&&(x0<=63.f), vx1 = (x1>=0.f)&&(x1<=63.f);
    int iy0 = (int)fminf(fmaxf(y0,0.f),63.f);
    int iy1 = (int)fminf(fmaxf(y1,0.f),63.f);
    int ix0 = (int)fminf(fmaxf(x0,0.f),63.f);
    int ix1 = (int)fminf(fmaxf(x1,0.f),63.f);
    sPk[t] = iy0 | (iy1<<6) | (ix0<<12) | (ix1<<18);
    sCf[t] = make_float4((vy0&&vx0)? (1.f-wy)*(1.f-wx)*mo : 0.f,
                         (vy0&&vx1)? (1.f-wy)*wx*mo       : 0.f,
                         (vy1&&vx0)? wy*(1.f-wx)*mo       : 0.f,
                         (vy1&&vx1)? wy*wx*mo             : 0.f);
  }
  __syncthreads();

  int lane = tid&63, wv = tid>>6, lo = lane&15, hi = lane>>4;
  float4v acc[4][4];
#pragma unroll
  for(int i=0;i<4;i++)
#pragma unroll
    for(int j=0;j<4;j++) acc[i][j] = (float4v){0.f,0.f,0.f,0.f};
  int cbase = (b*HW)<<8;

  uint4 wpre[4];
  uint2 cpre[2][4];
  { // prefetch kc=0
    const ushort* wp = Wdb;
#pragma unroll
    for(int it=0;it<4;it++){ int g = tid + it*256; wpre[it] = *(const uint4*)(wp + g*8); }
#pragma unroll
    for(int u=0;u<2;u++){
      int e = tid + u*256; int px = e>>3, seg = e&7;
      int pk = sPk[px];
      int coff = (seg<<2);
      int iy0 = pk&63, iy1 = (pk>>6)&63, ix0 = (pk>>12)&63, ix1 = (pk>>18)&63;
      cpre[u][0] = *(const uint2*)(xtb + cbase + (((iy0<<6)+ix0)<<8) + coff);
      cpre[u][1] = *(const uint2*)(xtb + cbase + (((iy0<<6)+ix1)<<8) + coff);
      cpre[u][2] = *(const uint2*)(xtb + cbase + (((iy1<<6)+ix0)<<8) + coff);
      cpre[u][3] = *(const uint2*)(xtb + cbase + (((iy1<<6)+ix1)<<8) + coff);
    }
  }
#pragma unroll 1
  for(int kc=0; kc<72; ++kc){
    // write staged regs -> LDS
#pragma unroll
    for(int it=0;it<4;it++){ int g = tid + it*256; *(uint4*)(&Ws[(g>>2)*LSTR + (g&3)*8]) = wpre[it]; }
    {
      int k = kc>>3;
#pragma unroll
      for(int u=0;u<2;u++){
        int e = tid + u*256; int px = e>>3, seg = e&7;
        float4 cf = sCf[(k<<6) + px];
        uint2 q00 = cpre[u][0], q01 = cpre[u][1], q10 = cpre[u][2], q11 = cpre[u][3];
        union{ ushort us[4]; uint2 q; } rr;
        rr.us[0] = f2bf(cf.x*bflo(q00.x)+cf.y*bflo(q01.x)+cf.z*bflo(q10.x)+cf.w*bflo(q11.x));
        rr.us[1] = f2bf(cf.x*bfhi(q00.x)+cf.y*bfhi(q01.x)+cf.z*bfhi(q10.x)+cf.w*bfhi(q11.x));
        rr.us[2] = f2bf(cf.x*bflo(q00.y)+cf.y*bflo(q01.y)+cf.z*bflo(q10.y)+cf.w*bflo(q11.y));
        rr.us[3] = f2bf(cf.x*bfhi(q00.y)+cf.y*bfhi(q01.y)+cf.z*bfhi(q10.y)+cf.w*bfhi(q11.y));
        *(uint2*)(&Vs[px*LSTR + (seg<<2)]) = rr.q;
      }
    }
    __syncthreads();
    int kn = kc<71 ? kc+1 : kc;
    { // prefetch kn
      const ushort* wp = Wdb + ((size_t)kn<<13);
#pragma unroll
      for(int it=0;it<4;it++){ int g = tid + it*256; wpre[it] = *(const uint4*)(wp + g*8); }
      int k = kn>>3, c0 = (kn&7)<<5;
#pragma unroll
      for(int u=0;u<2;u++){
        int e = tid + u*256; int px = e>>3, seg = e&7;
        int pk = sPk[(k<<6) + px];
        int coff = c0 + (seg<<2);
        int iy0 = pk&63, iy1 = (pk>>6)&63, ix0 = (pk>>12)&63, ix1 = (pk>>18)&63;
        cpre[u][0] = *(const uint2*)(xtb + cbase + (((iy0<<6)+ix0)<<8) + coff);
        cpre[u][1] = *(const uint2*)(xtb + cbase + (((iy0<<6)+ix1)<<8) + coff);
        cpre[u][2] = *(const uint2*)(xtb + cbase + (((iy1<<6)+ix0)<<8) + coff);
        cpre[u][3] = *(const uint2*)(xtb + cbase + (((iy1<<6)+ix1)<<8) + coff);
      }
    }
    // compute
    const ushort* ap = &Ws[(wv*64 + lo)*LSTR + hi*8];
    const ushort* bp = &Vs[lo*LSTR + hi*8];
    short8 bfr[4];
#pragma unroll
    for(int j=0;j<4;j++) bfr[j] = *(const short8*)(bp + j*16*LSTR);
#pragma unroll
    for(int i=0;i<4;i++){
      short8 afr = *(const short8*)(ap + i*16*LSTR);
#pragma unroll
      for(int j=0;j<4;j++)
        acc[i][j] = __builtin_amdgcn_mfma_f32_16x16x32_bf16(afr, bfr[j], acc[i][j], 0,0,0);
    }
    __syncthreads();
  }

#pragma unroll
  for(int i=0;i<4;i++){
    int ob = wv*64 + i*16 + hi*4;
#pragma unroll
    for(int r=0;r<4;r++){
      int o = ob + r;
      float bias = b_dcn[o];
      float* op = out1 + (size_t)(b*COUT + o)*HW + px0 + lo;
#pragma unroll
      for(int j=0;j<4;j++) op[j*16] = acc[i][j][r] + bias;
    }
  }
}

// ---------- batchnorm stats (f32 input, for out1) ----------
__global__ void k_bn_stats(const float* __restrict__ xin, float* __restrict__ stats, int per_b){
  int o = blockIdx.x, tid = threadIdx.x;
  float s=0.f, ss=0.f;
  for(int b=0;b<B_;b++){
    const float* p = xin + (size_t)(b*COUT+o)*per_b;
    for(int i=tid;i<per_b;i+=256){ float v = p[i]; s+=v; ss+=v*v; }
  }
  __shared__ float rs[256], rss[256];
  rs[tid]=s; rss[tid]=ss; __syncthreads();
  for(int st=128; st>0; st>>=1){
    if(tid<st){ rs[tid]+=rs[tid+st]; rss[tid]+=rss[tid+st]; }
    __syncthreads();
  }
  if(tid==0){
    float n = (float)(B_*per_b);
    float mean = rs[0]/n;
    float var  = rss[0]/n - mean*mean;
    stats[o*2] = mean; stats[o*2+1] = rsqrtf(var + 1e-5f);
  }
}

// ---------- batchnorm stats over bf16 ct [16 planes][o][4096] ----------
__global__ void k_bn_stats_ct(const ushort* __restrict__ ct, float* __restrict__ stats){
  int o = blockIdx.x, tid = threadIdx.x;
  float s=0.f, ss=0.f;
  for(int pl=0; pl<16; ++pl){
    const ushort* p = ct + (((size_t)(pl*256 + o))<<12);
    for(int i=tid*8; i<4096; i+=2048){
      uint4 v = *(const uint4*)(p + i);
      float f;
      f=bflo(v.x); s+=f; ss+=f*f;  f=bfhi(v.x); s+=f; ss+=f*f;
      f=bflo(v.y); s+=f; ss+=f*f;  f=bfhi(v.y); s+=f; ss+=f*f;
      f=bflo(v.z); s+=f; ss+=f*f;  f=bfhi(v.z); s+=f; ss+=f*f;
      f=bflo(v.w); s+=f; ss+=f*f;  f=bfhi(v.w); s+=f; ss+=f*f;
    }
  }
  __shared__ float rs[256], rss[256];
  rs[tid]=s; rss[tid]=ss; __syncthreads();
  for(int st=128; st>0; st>>=1){
    if(tid<st){ rs[tid]+=rs[tid+st]; rss[tid]+=rss[tid+st]; }
    __syncthreads();
  }
  if(tid==0){
    float n = (float)(16*4096);
    float mean = rs[0]/n;
    float var  = rss[0]/n - mean*mean;
    stats[o*2] = mean; stats[o*2+1] = rsqrtf(var + 1e-5f);
  }
}

// ---------- BN1 apply + relu + transpose -> y1b bf16 [b][p][c] ----------
__global__ void k_bn1_apply_t(const float* __restrict__ out1, const float* __restrict__ stats,
                              const float* __restrict__ gamma, const float* __restrict__ beta,
                              ushort* __restrict__ y1b){
  __shared__ float ts[32][33];
  int tx = threadIdx.x & 31, ty = threadIdx.x >> 5;
  int p0 = blockIdx.x*32, o0 = blockIdx.y*32, b = blockIdx.z;
#pragma unroll
  for(int q=0;q<4;q++){
    int oo = ty + q*8; int o = o0 + oo;
    float m = stats[o*2], rstd = stats[o*2+1];
    float scale = rstd * gamma[o];
    float shift = beta[o] - m * scale;
    float v = out1[(size_t)(b*COUT+o)*HW + p0+tx];
    ts[oo][tx] = fmaxf(v*scale + shift, 0.f);
  }
  __syncthreads();
#pragma unroll
  for(int q=0;q<4;q++){
    int pr = ty + q*8;
    y1b[((size_t)(b*HW + p0+pr)<<8) + o0+tx] = f2bf(ts[tx][pr]);
  }
}

// ---------- conv-transpose MFMA: Mb=256 o, Nb=256 px, one (b,pp); reg-prefetch ----------
// grid (16,4,4) = 256 blocks, 512 thr = 8 waves; wave: o-quarter (wv>>1), px-half (wv&1).
// Output: ct[pp*4+b][o][px] bf16, contiguous (parity interleave deferred to BN2).
__global__ __launch_bounds__(512) void k_convt_mfma(const ushort* __restrict__ y1b,
                        const ushort* __restrict__ WT2c,
                        ushort* __restrict__ ct){
  __shared__ ushort Ws[256*LSTR];
  __shared__ ushort Vs[256*LSTR];
  __shared__ int sIdx[1024];
  int tid = threadIdx.x;
  int px0 = blockIdx.x * 256;
  int b   = blockIdx.y;
  int pp  = blockIdx.z;
  int ph = pp>>1, pw = pp&1;

  for(int t=tid; t<1024; t+=512){
    int ab = t>>8, px = t&255;
    int a = ab>>1, bb = ab&1;
    int p = px0+px, r = p>>6, s = p&63;
    int ih = r + ph - 1 + a, iw = s + pw - 1 + bb;
    sIdx[t] = (ih>=0 && ih<64 && iw>=0 && iw<64) ? ((b*HW + ih*64+iw)<<8) : -1;
  }
  __syncthreads();

  int lane = tid&63, wv = tid>>6, lo = lane&15, hi = lane>>4;
  int om0 = (wv>>1)*64;
  int pn0 = (wv&1)*128;
  float4v acc[4][8];
#pragma unroll
  for(int i=0;i<4;i++)
#pragma unroll
    for(int j=0;j<8;j++) acc[i][j] = (float4v){0.f,0.f,0.f,0.f};

  const ushort* wbase = WT2c + ((size_t)pp<<18);
  uint4 wpre[2], vpre[2];
  { // prefetch kc=0
    wpre[0] = *(const uint4*)(wbase + tid*8);
    wpre[1] = *(const uint4*)(wbase + (tid+512)*8);
    int idx = sIdx[tid>>1];
    int co = (tid&1)*16;
    vpre[0] = vpre[1] = make_uint4(0,0,0,0);
    if(idx >= 0){
      vpre[0] = *(const uint4*)(y1b + idx + co);
      vpre[1] = *(const uint4*)(y1b + idx + co + 8);
    }
  }
#pragma unroll 1
  for(int kc=0; kc<32; ++kc){
    {
      int g1 = tid + 512;
      *(uint4*)(&Ws[(tid>>2)*LSTR + (tid&3)*8]) = wpre[0];
      *(uint4*)(&Ws[(g1>>2)*LSTR + (g1&3)*8])   = wpre[1];
      int vpx = tid>>1, co = (tid&1)*16;
      *(uint4*)(&Vs[vpx*LSTR + co])     = vpre[0];
      *(uint4*)(&Vs[vpx*LSTR + co + 8]) = vpre[1];
    }
    __syncthreads();
    int kn = kc<31 ? kc+1 : kc;
    {
      const ushort* wp = wbase + (kn<<13);
      wpre[0] = *(const uint4*)(wp + tid*8);
      wpre[1] = *(const uint4*)(wp + (tid+512)*8);
      int ab = kn>>3, c0 = (kn&7)<<5;
      int idx = sIdx[(ab<<8) + (tid>>1)];
      int co = c0 + (tid&1)*16;
      vpre[0] = vpre[1] = make_uint4(0,0,0,0);
      if(idx >= 0){
        vpre[0] = *(const uint4*)(y1b + idx + co);
        vpre[1] = *(const uint4*)(y1b + idx + co + 8);
      }
    }
    const ushort* ap = &Ws[(om0 + lo)*LSTR + hi*8];
    const ushort* bp = &Vs[(pn0 + lo)*LSTR + hi*8];
    short8 bfr[8];
#pragma unroll
    for(int j=0;j<8;j++) bfr[j] = *(const short8*)(bp + j*16*LSTR);
#pragma unroll
    for(int i=0;i<4;i++){
      short8 afr = *(const short8*)(ap + i*16*LSTR);
#pragma unroll
      for(int j=0;j<8;j++)
        acc[i][j] = __builtin_amdgcn_mfma_f32_16x16x32_bf16(afr, bfr[j], acc[i][j], 0,0,0);
    }
    __syncthreads();
  }

  ushort* cb = ct + (((size_t)(pp*4 + b)*256)<<12);
#pragma unroll
  for(int i=0;i<4;i++){
#pragma unroll
    for(int r=0;r<4;r++){
      int o = om0 + i*16 + hi*4 + r;
      ushort* row = cb + ((size_t)o<<12) + px0 + pn0 + lo;
#pragma unroll
      for(int j=0;j<8;j++) row[j*16] = f2bf(acc[i][j][r]);
    }
  }
}

// ---------- BN2 apply + relu + parity interleave: ct bf16 -> out f32 ----------
__global__ void k_bn2_apply(const ushort* __restrict__ ct, const float* __restrict__ stats,
                            const float* __restrict__ gamma, const float* __restrict__ beta,
                            float* __restrict__ out){
  int gid = blockIdx.x*256 + threadIdx.x;   // grid 16384
  int e4 = gid<<2;
  int b = e4>>22, o = (e4>>14)&255, q = e4&16383;
  int H2 = q>>7, W2 = q&127;
  int r = H2>>1, ph = H2&1, s0 = W2>>1;
  size_t base0 = (((size_t)((ph*2)*4 + b)*256 + o)<<12) + r*64 + s0;
  unsigned u0 = *(const unsigned*)(ct + base0);
  unsigned u1 = *(const unsigned*)(ct + base0 + ((size_t)4<<20));
  float m = stats[o*2], rstd = stats[o*2+1];
  float sc = rstd * gamma[o];
  float sh = beta[o] - m * sc;
  float4 v;
  v.x = fmaxf(bflo(u0)*sc + sh, 0.f);
  v.y = fmaxf(bflo(u1)*sc + sh, 0.f);
  v.z = fmaxf(bfhi(u0)*sc + sh, 0.f);
  v.w = fmaxf(bfhi(u1)*sc + sh, 0.f);
  *(float4*)(out + e4) = v;
}

extern "C" void kernel_launch(void* const* d_in, const int* in_sizes, int n_in,
                              void* d_out, int out_size, void* d_ws, size_t ws_size,
                              hipStream_t stream){
  (void)in_sizes; (void)n_in; (void)out_size; (void)ws_size;
  const float* x     = (const float*)d_in[0];
  const float* w_off = (const float*)d_in[1];
  const float* b_off = (const float*)d_in[2];
  const float* w_dcn = (const float*)d_in[3];
  const float* b_dcn = (const float*)d_in[4];
  const float* gamma1= (const float*)d_in[5];
  const float* beta1 = (const float*)d_in[6];
  const float* w_up  = (const float*)d_in[7];
  const float* gamma2= (const float*)d_in[8];
  const float* beta2 = (const float*)d_in[9];
  float* out = (float*)d_out;

  // Workspace (floats). ct (bf16, 32 MB = 8388608 floats) aliases om+xtb+out1,
  // all of which are dead before k_convt_mfma runs.
  float* ws   = (float*)d_ws;
  ushort* ct  = (ushort*)ws;                       // [0, 8388608) floats
  float* om   = ws;                                // 442368 floats
  ushort* xtb = (ushort*)(ws + 442368);            // 4194304 bf16 = 2097152 floats
  float* out1 = ws + 442368 + 2097152;             // 4194304 floats, ends 6733824 < 8388608
  float* base2 = ws + 8388608;
  ushort* y1b  = (ushort*)base2;                                   // 4194304 bf16
  ushort* WT2c = (ushort*)(base2 + 2097152);                       // 1048576 bf16
  ushort* Wdb  = (ushort*)(base2 + 2097152 + 524288);              // 589824 bf16
  ushort* Wob  = (ushort*)(base2 + 2097152 + 524288 + 294912);     // 73728 bf16
  float* st1   = base2 + 2097152 + 524288 + 294912 + 36864;        // 512
  float* st2   = st1 + 512;                                        // 512

  k_transpose_x <<<dim3(128,8,4), 256, 0, stream>>>(x, xtb);
  k_build_Wob   <<<288,  256, 0, stream>>>(w_off, Wob);
  k_build_Wdb   <<<2304, 256, 0, stream>>>(w_dcn, Wdb);
  k_build_WT2c  <<<4096, 256, 0, stream>>>(w_up, WT2c);
  k_offset_mfma <<<dim3(64,4),  256, 0, stream>>>(xtb, Wob, om);
  k_dcn_mfma    <<<dim3(64,4),  256, 0, stream>>>(xtb, om, b_off, Wdb, b_dcn, out1);
  k_bn_stats    <<<256,  256, 0, stream>>>(out1, st1, 4096);
  k_bn1_apply_t <<<dim3(128,8,4), 256, 0, stream>>>(out1, st1, gamma1, beta1, y1b);
  k_convt_mfma  <<<dim3(16,4,4),  512, 0, stream>>>(y1b, WT2c, ct);
  k_bn_stats_ct <<<256,  256, 0, stream>>>(ct, st2);
  k_bn2_apply   <<<16384,256, 0, stream>>>(ct, st2, gamma2, beta2, out);
}